// Round 1
// baseline (6333.274 us; speedup 1.0000x reference)
//
#include <hip/hip_runtime.h>
#include <hip/hip_bf16.h>
#include <math.h>

// ---------------------------------------------------------------------------
// DeepOdoModel: conv1(7->128,k11)+pool2 -> conv2(128->256,k9)+pool2 -> fc1 ->
// fc2 -> 512-step GRUCell (B=16,H=512) -> fc3.  All fp32 this round.
// ---------------------------------------------------------------------------

#define B_ 16
#define T_ 512
#define N_ 8192          // B*T frames
#define H_ 512

// ---------------- conv1 + pool ----------------
// x[n][c][l] = phone[n][l][c], l<50, c<7
// y[n,o,pos] = b1[o] + sum_{i<7,k<11} x[n][i][pos+k]*w1[o][i][k], pos<40
// out1[n][o][p] = max(y[...,2p], y[...,2p+1]), p<20
__global__ __launch_bounds__(256) void conv1_kernel(
    const float* __restrict__ phone, const float* __restrict__ w1,
    const float* __restrict__ b1, float* __restrict__ out1) {
  __shared__ float xs[7][52];
  __shared__ float ws[128 * 77];
  __shared__ float bs[128];
  const int n = blockIdx.x;
  const int tid = threadIdx.x;
  for (int idx = tid; idx < 350; idx += 256) {
    int l = idx / 7, c = idx - l * 7;
    xs[c][l] = phone[(size_t)n * 350 + idx];
  }
  for (int idx = tid; idx < 9856; idx += 256) ws[idx] = w1[idx];
  if (tid < 128) bs[tid] = b1[tid];
  __syncthreads();

  const int o = tid >> 1, ph = tid & 1;
  float acc0[10], acc1[10];
#pragma unroll
  for (int q = 0; q < 10; ++q) { acc0[q] = 0.f; acc1[q] = 0.f; }
  const float* wo = ws + o * 77;
  for (int i = 0; i < 7; ++i) {
    float wr[11];
#pragma unroll
    for (int k = 0; k < 11; ++k) wr[k] = wo[i * 11 + k];
#pragma unroll
    for (int q = 0; q < 10; ++q) {
      int p = ph * 10 + q;
      int base = 2 * p;
      float xv[12];
#pragma unroll
      for (int j = 0; j < 12; ++j) xv[j] = xs[i][base + j];
      float s0 = 0.f, s1 = 0.f;
#pragma unroll
      for (int k = 0; k < 11; ++k) {
        s0 += xv[k] * wr[k];
        s1 += xv[k + 1] * wr[k];
      }
      acc0[q] += s0;
      acc1[q] += s1;
    }
  }
  const float bb = bs[o];
#pragma unroll
  for (int q = 0; q < 10; ++q) {
    int p = ph * 10 + q;
    out1[((size_t)n * 128 + o) * 20 + p] = fmaxf(acc0[q], acc1[q]) + bb;
  }
}

// ---------------- generic tiled fp32 GEMM: C = A @ W^T + bias ----------------
// AMODE 0: A is [M][lda] row-major.  AMODE 1: implicit im2col from out1 for
//   conv2 (m = n*12+pos, kk = i*9+k, A = out1[n][i][pos+k], K=1152).
// EMODE 0: C[m][ldc] = acc + bias.  EMODE 1: pooled-store for conv2:
//   feat2[n][o*6 + p] = max over pos-pair + bias.
template <int AMODE, int EMODE>
__global__ __launch_bounds__(256) void gemm_tile(
    const float* __restrict__ A, const float* __restrict__ W,
    const float* __restrict__ bias, float* __restrict__ C,
    int K, int lda, int ldc) {
  __shared__ float As[16][132];
  __shared__ float Bs[16][68];
  const int tid = threadIdx.x;
  const int tx = tid & 15, ty = tid >> 4;
  const int bm0 = blockIdx.x * 128, bn0 = blockIdx.y * 64;
  float acc[8][4];
#pragma unroll
  for (int r = 0; r < 8; ++r)
#pragma unroll
    for (int c = 0; c < 4; ++c) acc[r][c] = 0.f;

  const int nkt = K >> 4;
  for (int kt = 0; kt < nkt; ++kt) {
    const int k0 = kt << 4;
    // stage A tile -> As[kk][row]
#pragma unroll
    for (int q = 0; q < 2; ++q) {
      int f4 = tid + q * 256;
      int row = f4 >> 2, kk0 = (f4 & 3) << 2;
      if (AMODE == 0) {
        float4 v = *(const float4*)(A + (size_t)(bm0 + row) * lda + k0 + kk0);
        As[kk0 + 0][row] = v.x; As[kk0 + 1][row] = v.y;
        As[kk0 + 2][row] = v.z; As[kk0 + 3][row] = v.w;
      } else {
        int m = bm0 + row;
        int n = m / 12, pos = m - n * 12;
#pragma unroll
        for (int j = 0; j < 4; ++j) {
          int kk = k0 + kk0 + j;
          int i = kk / 9, k = kk - i * 9;
          As[kk0 + j][row] = A[((size_t)n * 128 + i) * 20 + pos + k];
        }
      }
    }
    // stage B tile (W row-major [Nc][K]) -> Bs[kk][col]
    {
      int wrow = tid >> 2, kk0 = (tid & 3) << 2;
      float4 v = *(const float4*)(W + (size_t)(bn0 + wrow) * K + k0 + kk0);
      Bs[kk0 + 0][wrow] = v.x; Bs[kk0 + 1][wrow] = v.y;
      Bs[kk0 + 2][wrow] = v.z; Bs[kk0 + 3][wrow] = v.w;
    }
    __syncthreads();
#pragma unroll
    for (int kk = 0; kk < 16; ++kk) {
      float4 a0 = *(const float4*)&As[kk][ty * 8];
      float4 a1 = *(const float4*)&As[kk][ty * 8 + 4];
      float4 bv = *(const float4*)&Bs[kk][tx * 4];
      float ar[8] = {a0.x, a0.y, a0.z, a0.w, a1.x, a1.y, a1.z, a1.w};
      float bc[4] = {bv.x, bv.y, bv.z, bv.w};
#pragma unroll
      for (int r = 0; r < 8; ++r)
#pragma unroll
        for (int c = 0; c < 4; ++c) acc[r][c] += ar[r] * bc[c];
    }
    __syncthreads();
  }

  float4 bv = *(const float4*)(bias + bn0 + tx * 4);
  float bb[4] = {bv.x, bv.y, bv.z, bv.w};
  if (EMODE == 0) {
#pragma unroll
    for (int r = 0; r < 8; ++r) {
      int m = bm0 + ty * 8 + r;
      float4 o4 = make_float4(acc[r][0] + bb[0], acc[r][1] + bb[1],
                              acc[r][2] + bb[2], acc[r][3] + bb[3]);
      *(float4*)(C + (size_t)m * ldc + bn0 + tx * 4) = o4;
    }
  } else {
#pragma unroll
    for (int rp = 0; rp < 4; ++rp) {
      int m0 = bm0 + ty * 8 + rp * 2;
      int n = m0 / 12, pos = m0 - n * 12;
      int p = pos >> 1;
#pragma unroll
      for (int c = 0; c < 4; ++c) {
        int o = bn0 + tx * 4 + c;
        float v = fmaxf(acc[rp * 2][c], acc[rp * 2 + 1][c]) + bb[c];
        C[(size_t)n * 1536 + o * 6 + p] = v;
      }
    }
  }
}

// ---------------- GRU one timestep ----------------
// 64 WGs, WG w owns h-dims J in [w*8, w*8+8).  384 threads = 24 rows x 16 b.
__global__ __launch_bounds__(384) void gru_step(
    const float* __restrict__ h_prev, const float* __restrict__ gi,
    const float* __restrict__ whh, const float* __restrict__ bhh,
    float* __restrict__ hs, int t) {
  __shared__ float h_lds[16 * 516];
  __shared__ float gh_lds[24 * 16];
  const int tid = threadIdx.x;
  for (int idx = tid; idx < 2048; idx += 384) {
    float4 v = *(const float4*)(h_prev + (size_t)idx * 4);
    int b = idx >> 7, col = (idx & 127) << 2;
    *(float4*)&h_lds[b * 516 + col] = v;
  }
  __syncthreads();
  {
    const int b = tid & 15, r = tid >> 4;  // r < 24
    const int J = (blockIdx.x << 3) + (r & 7);
    const int o = (r >> 3) * 512 + J;
    float acc = bhh[o];
    const float4* wr = (const float4*)(whh + (size_t)o * 512);
    const float4* hr = (const float4*)&h_lds[b * 516];
#pragma unroll 8
    for (int kc = 0; kc < 128; ++kc) {
      float4 w = wr[kc], h = hr[kc];
      acc += w.x * h.x + w.y * h.y + w.z * h.z + w.w * h.w;
    }
    gh_lds[r * 16 + b] = acc;
  }
  __syncthreads();
  if (tid < 128) {
    const int b = tid & 15, js = tid >> 4;
    const int J = (blockIdx.x << 3) + js;
    const size_t gib = ((size_t)b * T_ + t) * 1536;
    float grr = gh_lds[js * 16 + b];
    float gzz = gh_lds[(8 + js) * 16 + b];
    float gnn = gh_lds[(16 + js) * 16 + b];
    float ir = gi[gib + J], iz = gi[gib + 512 + J], inn = gi[gib + 1024 + J];
    float rg = 1.f / (1.f + expf(-(ir + grr)));
    float zg = 1.f / (1.f + expf(-(iz + gzz)));
    float ng = tanhf(inn + rg * gnn);
    float ho = h_lds[b * 516 + J];
    hs[((size_t)t * 16 + b) * 512 + J] = (1.f - zg) * ng + zg * ho;
  }
}

// ---------------- fc3: out[b*512+t] = dot(hs[t][b], w3) + b3 ----------------
__global__ __launch_bounds__(256) void fc3_kernel(
    const float* __restrict__ hs, const float* __restrict__ w3,
    const float* __restrict__ b3, float* __restrict__ out) {
  __shared__ float w[512];
  const int tid = threadIdx.x;
  w[tid] = w3[tid];
  w[tid + 256] = w3[tid + 256];
  __syncthreads();
  const int g = blockIdx.x * 256 + tid;  // g = b*512 + t
  const int b = g >> 9, t = g & 511;
  const float4* hr = (const float4*)(hs + ((size_t)t * 16 + b) * 512);
  const float4* wr = (const float4*)w;
  float acc = 0.f;
#pragma unroll 8
  for (int kc = 0; kc < 128; ++kc) {
    float4 h = hr[kc], ww = wr[kc];
    acc += h.x * ww.x + h.y * ww.y + h.z * ww.z + h.w * ww.w;
  }
  out[g] = acc + b3[0];
}

// ---------------------------------------------------------------------------
extern "C" void kernel_launch(void* const* d_in, const int* in_sizes, int n_in,
                              void* d_out, int out_size, void* d_ws,
                              size_t ws_size, hipStream_t stream) {
  const float* phone = (const float*)d_in[0];
  const float* h0    = (const float*)d_in[1];
  const float* w1    = (const float*)d_in[2];
  const float* b1    = (const float*)d_in[3];
  const float* w2    = (const float*)d_in[4];
  const float* b2    = (const float*)d_in[5];
  const float* fc1w  = (const float*)d_in[6];
  const float* fc1b  = (const float*)d_in[7];
  const float* fc2w  = (const float*)d_in[8];
  const float* fc2b  = (const float*)d_in[9];
  const float* wih   = (const float*)d_in[10];
  const float* whh   = (const float*)d_in[11];
  const float* bih   = (const float*)d_in[12];
  const float* bhh   = (const float*)d_in[13];
  const float* w3    = (const float*)d_in[14];
  const float* b3    = (const float*)d_in[15];
  float* out = (float*)d_out;

  char* ws = (char*)d_ws;
  float* out1  = (float*)(ws + 0);           // 8192*128*20*4  = 83,886,080
  float* feat2 = (float*)(ws + 83886080);    // 8192*1536*4    = 50,331,648
  float* feat3 = (float*)(ws + 0);           // 8192*1024*4    = 33,554,432 (reuses out1)
  float* feat4 = (float*)(ws + 33554432);    // 8192*512*4     = 16,777,216
  float* gibuf = (float*)(ws + 83886080);    // 8192*1536*4    (reuses feat2)
  float* hsbuf = (float*)(ws + 134217728);   // 512*16*512*4   = 16,777,216

  // conv1 + pool
  conv1_kernel<<<N_, 256, 0, stream>>>(phone, w1, b1, out1);
  // conv2 + pool as im2col GEMM: M=98304, K=1152, Nc=256
  gemm_tile<1, 1><<<dim3(768, 4), 256, 0, stream>>>(out1, w2, b2, feat2, 1152, 0, 0);
  // fc1: M=8192, K=1536, Nc=1024
  gemm_tile<0, 0><<<dim3(64, 16), 256, 0, stream>>>(feat2, fc1w, fc1b, feat3, 1536, 1536, 1024);
  // fc2: M=8192, K=1024, Nc=512
  gemm_tile<0, 0><<<dim3(64, 8), 256, 0, stream>>>(feat3, fc2w, fc2b, feat4, 1024, 1024, 512);
  // gi = feat @ Wih^T + bih: M=8192, K=512, Nc=1536
  gemm_tile<0, 0><<<dim3(64, 24), 256, 0, stream>>>(feat4, wih, bih, gibuf, 512, 512, 1536);

  // sequential GRU: 512 step kernels
  for (int t = 0; t < T_; ++t) {
    const float* hp = (t == 0) ? h0 : (hsbuf + (size_t)(t - 1) * 16 * 512);
    gru_step<<<64, 384, 0, stream>>>(hp, gibuf, whh, bhh, hsbuf, t);
  }

  // fc3
  fc3_kernel<<<32, 256, 0, stream>>>(hsbuf, w3, b3, out);
}

// Round 2
// 2966.530 us; speedup vs baseline: 2.1349x; 2.1349x over previous
//
#include <hip/hip_runtime.h>
#include <hip/hip_bf16.h>
#include <math.h>
#include <stdint.h>

typedef __attribute__((ext_vector_type(8))) short short8;
typedef __attribute__((ext_vector_type(4))) float f32x4;

#define T_ 512

__device__ __forceinline__ unsigned short bf16rn(float f) {
  union { float f; unsigned u; } x; x.f = f;
  unsigned r = x.u + 0x7FFF + ((x.u >> 16) & 1);
  return (unsigned short)(r >> 16);
}

__device__ __forceinline__ void gload16(const void* gsrc, void* ldst) {
  __builtin_amdgcn_global_load_lds(
      (const __attribute__((address_space(1))) unsigned int*)gsrc,
      (__attribute__((address_space(3))) unsigned int*)ldst, 16, 0, 0);
}

// ---------------- conv1 + pool (fp32 math, bf16 out) ----------------
__global__ __launch_bounds__(256) void conv1_kernel(
    const float* __restrict__ phone, const float* __restrict__ w1,
    const float* __restrict__ b1, ushort* __restrict__ out1b) {
  __shared__ float xs[7][52];
  __shared__ float ws[128 * 77];
  __shared__ float bs[128];
  const int n = blockIdx.x;
  const int tid = threadIdx.x;
  for (int idx = tid; idx < 350; idx += 256) {
    int l = idx / 7, c = idx - l * 7;
    xs[c][l] = phone[(size_t)n * 350 + idx];
  }
  for (int idx = tid; idx < 9856; idx += 256) ws[idx] = w1[idx];
  if (tid < 128) bs[tid] = b1[tid];
  __syncthreads();

  const int o = tid >> 1, ph = tid & 1;
  float acc0[10], acc1[10];
#pragma unroll
  for (int q = 0; q < 10; ++q) { acc0[q] = 0.f; acc1[q] = 0.f; }
  const float* wo = ws + o * 77;
  for (int i = 0; i < 7; ++i) {
    float wr[11];
#pragma unroll
    for (int k = 0; k < 11; ++k) wr[k] = wo[i * 11 + k];
#pragma unroll
    for (int q = 0; q < 10; ++q) {
      int p = ph * 10 + q;
      int base = 2 * p;
      float xv[12];
#pragma unroll
      for (int j = 0; j < 12; ++j) xv[j] = xs[i][base + j];
      float s0 = 0.f, s1 = 0.f;
#pragma unroll
      for (int k = 0; k < 11; ++k) {
        s0 += xv[k] * wr[k];
        s1 += xv[k + 1] * wr[k];
      }
      acc0[q] += s0;
      acc1[q] += s1;
    }
  }
  const float bb = bs[o];
#pragma unroll
  for (int q = 0; q < 10; ++q) {
    int p = ph * 10 + q;
    out1b[((size_t)n * 128 + o) * 20 + p] = bf16rn(fmaxf(acc0[q], acc1[q]) + bb);
  }
}

// ---------------- fp32 -> bf16 convert ----------------
__global__ __launch_bounds__(256) void f32_to_bf16(
    const float* __restrict__ src, ushort* __restrict__ dst, int n4) {
  int i = blockIdx.x * 256 + threadIdx.x;
  if (i < n4) {
    float4 v = ((const float4*)src)[i];
    ushort4 o;
    o.x = bf16rn(v.x); o.y = bf16rn(v.y); o.z = bf16rn(v.z); o.w = bf16rn(v.w);
    ((ushort4*)dst)[i] = o;
  }
}

// ---------------- bf16 MFMA GEMM: C = A @ W^T + bias ----------------
// AM 0: A row-major [M][lda] bf16, staged via global_load_lds (swizzled src).
// AM 1: im2col gather from out1b (conv2): m=(n,pos), kk=i*9+kp.
// EM 0: bf16 C[m][ldc].  EM 1: conv2 pool-store bf16 feat2[n][col*6+p].
// EM 2: fp32 transposed gi store C[(t*16+b)*1536+col].
template <int AM, int EM>
__global__ __launch_bounds__(256) void gemm_bf16(
    const ushort* __restrict__ A, const ushort* __restrict__ W,
    const float* __restrict__ bias, void* __restrict__ Cout,
    int K, int lda, int ldc) {
  __shared__ ushort As[128 * 64];
  __shared__ ushort Bs[128 * 64];
  const int tid = threadIdx.x;
  const int l = tid & 63, wv = tid >> 6;
  const int wr = wv >> 1, wc = wv & 1;
  const int fr = l & 15, fq = l >> 4;
  const int bm0 = blockIdx.x * 128, bn0 = blockIdx.y * 128;

  f32x4 acc[4][4];
#pragma unroll
  for (int mi = 0; mi < 4; ++mi)
#pragma unroll
    for (int ni = 0; ni < 4; ++ni) acc[mi][ni] = (f32x4)0.f;

  const int pr8 = l >> 3;  // 0..7
  const int pc = l & 7;
  const int nkt = K >> 6;
  for (int kt = 0; kt < nkt; ++kt) {
    const int k0 = kt << 6;
    // stage B (weights, [N][K] bf16) via global_load_lds, swizzled source
#pragma unroll
    for (int i = 0; i < 4; ++i) {
      int q = wv * 4 + i;
      int prow = q * 8 + pr8;
      int lc = pc ^ (prow & 7);
      gload16(W + (size_t)(bn0 + prow) * K + k0 + lc * 8, &Bs[q * 512]);
    }
    if (AM == 0) {
#pragma unroll
      for (int i = 0; i < 4; ++i) {
        int q = wv * 4 + i;
        int prow = q * 8 + pr8;
        int lc = pc ^ (prow & 7);
        gload16(A + (size_t)(bm0 + prow) * lda + k0 + lc * 8, &As[q * 512]);
      }
    } else {
      // gather im2col tile: rows m=bm0+row, cols kk=k0+c
#pragma unroll
      for (int q = 0; q < 32; ++q) {
        int idx = tid + q * 256;
        int row = idx >> 6, c = idx & 63;
        int m = bm0 + row;
        int n = m / 12, pos = m - n * 12;
        int kk = k0 + c;
        int i2 = kk / 9, kp = kk - i2 * 9;
        As[row * 64 + (((c >> 3) ^ (row & 7)) << 3) + (c & 7)] =
            A[(size_t)n * 2560 + i2 * 20 + pos + kp];
      }
    }
    __syncthreads();
#pragma unroll
    for (int ks = 0; ks < 2; ++ks) {
      short8 af[4], bfr[4];
#pragma unroll
      for (int mi = 0; mi < 4; ++mi) {
        int row = wr * 64 + mi * 16 + fr;
        af[mi] = *(const short8*)&As[row * 64 + (((ks * 4 + fq) ^ (row & 7)) << 3)];
      }
#pragma unroll
      for (int ni = 0; ni < 4; ++ni) {
        int row = wc * 64 + ni * 16 + fr;
        bfr[ni] = *(const short8*)&Bs[row * 64 + (((ks * 4 + fq) ^ (row & 7)) << 3)];
      }
#pragma unroll
      for (int mi = 0; mi < 4; ++mi)
#pragma unroll
        for (int ni = 0; ni < 4; ++ni)
          acc[mi][ni] = __builtin_amdgcn_mfma_f32_16x16x32_bf16(
              af[mi], bfr[ni], acc[mi][ni], 0, 0, 0);
    }
    __syncthreads();
  }

#pragma unroll
  for (int ni = 0; ni < 4; ++ni) {
    int col = bn0 + wc * 64 + ni * 16 + fr;
    float bv = bias[col];
#pragma unroll
    for (int mi = 0; mi < 4; ++mi) {
      int mbase = bm0 + wr * 64 + mi * 16 + fq * 4;
      if (EM == 0) {
        ushort* C = (ushort*)Cout;
#pragma unroll
        for (int j = 0; j < 4; ++j)
          C[(size_t)(mbase + j) * ldc + col] = bf16rn(acc[mi][ni][j] + bv);
      } else if (EM == 1) {
        ushort* C = (ushort*)Cout;
#pragma unroll
        for (int j = 0; j < 4; j += 2) {
          int m = mbase + j;
          int n = m / 12, pos = m - n * 12;
          float v = fmaxf(acc[mi][ni][j], acc[mi][ni][j + 1]) + bv;
          C[(size_t)n * 1536 + col * 6 + (pos >> 1)] = bf16rn(v);
        }
      } else {
        float* C = (float*)Cout;
#pragma unroll
        for (int j = 0; j < 4; ++j) {
          int m = mbase + j;
          int b = m >> 9, tt = m & 511;
          C[((size_t)tt * 16 + b) * 1536 + col] = acc[mi][ni][j] + bv;
        }
      }
    }
  }
}

// ---------------- persistent GRU: 16 WGs, grid barrier per step ----------------
// WG w owns h-dims j in [w*32, w*32+32).  384 thr = 6 waves; wave v=(g,jt):
// gate g=v>>1, 16 cols o = g*512 + w*32 + (v&1)*16 + (l&15).
// Whh kept in registers as bf16 MFMA B-fragments for all 512 steps.
__global__ __launch_bounds__(384) void gru_persistent(
    const float* __restrict__ h0, const float* __restrict__ gi,
    const float* __restrict__ whh, const float* __restrict__ bhh,
    float* __restrict__ hsbuf, unsigned* __restrict__ bar) {
  __shared__ ushort hpack[16 * 64 * 8];  // [s][lane][8] bf16 A-fragments
  __shared__ float gh_lds[6 * 256];      // [tile][b][16]
  const int tid = threadIdx.x;
  const int w = blockIdx.x;              // 0..15
  const int l = tid & 63, v = tid >> 6;  // v 0..5
  const int fr = l & 15, fq = l >> 4;
  const int g = v >> 1;
  const int colbase = g * 512 + w * 32 + (v & 1) * 16;
  const int o = colbase + fr;

  // pre-pack Whh B-fragments into registers (persistent)
  short8 bfrag[16];
#pragma unroll
  for (int s = 0; s < 16; ++s) {
    const float* wp = whh + (size_t)o * 512 + s * 32 + fq * 8;
    float4 w0 = *(const float4*)wp;
    float4 w1 = *(const float4*)(wp + 4);
    short8 bb;
    bb[0] = (short)bf16rn(w0.x); bb[1] = (short)bf16rn(w0.y);
    bb[2] = (short)bf16rn(w0.z); bb[3] = (short)bf16rn(w0.w);
    bb[4] = (short)bf16rn(w1.x); bb[5] = (short)bf16rn(w1.y);
    bb[6] = (short)bf16rn(w1.z); bb[7] = (short)bf16rn(w1.w);
    bfrag[s] = bb;
  }
  const float bo = bhh[o];

  for (int t = 0; t < T_; ++t) {
    const float* hp = t ? (hsbuf + (size_t)(t - 1) * 8192) : h0;
    // prefetch gi + h_prev (registers; overlaps staging + MFMA)
    float pir[2], piz[2], pin[2], phv[2];
#pragma unroll
    for (int pp = 0; pp < 2; ++pp) {
      int p = tid + pp * 384;
      if (p < 512) {
        int jl = p & 31, b = p >> 5;
        int jj = w * 32 + jl;
        const float* gb = gi + ((size_t)t * 16 + b) * 1536;
        pir[pp] = gb[jj]; piz[pp] = gb[512 + jj]; pin[pp] = gb[1024 + jj];
        phv[pp] = hp[(size_t)b * 512 + jj];
      }
    }
    // stage h (fp32 global) -> hpack (bf16 fragment order)
    for (int idx = tid; idx < 2048; idx += 384) {
      float4 hv = *(const float4*)(hp + (size_t)idx * 4);
      int b = idx >> 7, k = (idx & 127) * 4;
      int s = k >> 5, lane = b | (((k >> 3) & 3) << 4), j0 = k & 7;
      ushort4 uu;
      uu.x = bf16rn(hv.x); uu.y = bf16rn(hv.y);
      uu.z = bf16rn(hv.z); uu.w = bf16rn(hv.w);
      *(ushort4*)&hpack[((s * 64 + lane) << 3) + j0] = uu;
    }
    __syncthreads();
    // gh = h @ Whh_slice^T   (16 MFMA per wave)
    f32x4 acc = (f32x4)0.f;
#pragma unroll
    for (int s = 0; s < 16; ++s) {
      short8 af = *(const short8*)&hpack[(s * 64 + l) << 3];
      acc = __builtin_amdgcn_mfma_f32_16x16x32_bf16(af, bfrag[s], acc, 0, 0, 0);
    }
#pragma unroll
    for (int j = 0; j < 4; ++j)
      gh_lds[v * 256 + (fq * 4 + j) * 16 + fr] = acc[j] + bo;
    __syncthreads();
    // elementwise gate math (fp32 state)
#pragma unroll
    for (int pp = 0; pp < 2; ++pp) {
      int p = tid + pp * 384;
      if (p < 512) {
        int jl = p & 31, b = p >> 5;
        int tb = jl >> 4, jj = jl & 15;
        float rr = gh_lds[(0 + tb) * 256 + b * 16 + jj];
        float zz = gh_lds[(2 + tb) * 256 + b * 16 + jj];
        float nn = gh_lds[(4 + tb) * 256 + b * 16 + jj];
        float rg = 1.f / (1.f + __expf(-(pir[pp] + rr)));
        float zg = 1.f / (1.f + __expf(-(piz[pp] + zz)));
        float ng = tanhf(pin[pp] + rg * nn);
        float hn = (1.f - zg) * ng + zg * phv[pp];
        hsbuf[((size_t)t * 16 + b) * 512 + w * 32 + jl] = hn;
      }
    }
    // device-scope grid barrier (16 co-resident WGs)
    __syncthreads();
    if (tid == 0) {
      __threadfence();
      __hip_atomic_fetch_add(bar, 1u, __ATOMIC_RELEASE, __HIP_MEMORY_SCOPE_AGENT);
      unsigned tgt = 16u * (unsigned)(t + 1);
      while (__hip_atomic_load(bar, __ATOMIC_ACQUIRE, __HIP_MEMORY_SCOPE_AGENT) < tgt)
        __builtin_amdgcn_s_sleep(2);
      __threadfence();
    }
    __syncthreads();
  }
}

// ---------------- fc3 ----------------
__global__ __launch_bounds__(256) void fc3_kernel(
    const float* __restrict__ hs, const float* __restrict__ w3,
    const float* __restrict__ b3, float* __restrict__ out) {
  __shared__ float w[512];
  const int tid = threadIdx.x;
  w[tid] = w3[tid];
  w[tid + 256] = w3[tid + 256];
  __syncthreads();
  const int gidx = blockIdx.x * 256 + tid;  // b*512 + t
  const int b = gidx >> 9, t = gidx & 511;
  const float4* hr = (const float4*)(hs + ((size_t)t * 16 + b) * 512);
  const float4* wr = (const float4*)w;
  float acc = 0.f;
#pragma unroll 8
  for (int kc = 0; kc < 128; ++kc) {
    float4 h = hr[kc], ww = wr[kc];
    acc += h.x * ww.x + h.y * ww.y + h.z * ww.z + h.w * ww.w;
  }
  out[gidx] = acc + b3[0];
}

// ---------------------------------------------------------------------------
extern "C" void kernel_launch(void* const* d_in, const int* in_sizes, int n_in,
                              void* d_out, int out_size, void* d_ws,
                              size_t ws_size, hipStream_t stream) {
  const float* phone = (const float*)d_in[0];
  const float* h0    = (const float*)d_in[1];
  const float* w1    = (const float*)d_in[2];
  const float* b1    = (const float*)d_in[3];
  const float* w2    = (const float*)d_in[4];
  const float* b2    = (const float*)d_in[5];
  const float* fc1w  = (const float*)d_in[6];
  const float* fc1b  = (const float*)d_in[7];
  const float* fc2w  = (const float*)d_in[8];
  const float* fc2b  = (const float*)d_in[9];
  const float* wih   = (const float*)d_in[10];
  const float* whh   = (const float*)d_in[11];
  const float* bih   = (const float*)d_in[12];
  const float* bhh   = (const float*)d_in[13];
  const float* w3    = (const float*)d_in[14];
  const float* b3    = (const float*)d_in[15];
  float* out = (float*)d_out;

  char* ws = (char*)d_ws;
  ushort* out1b = (ushort*)(ws + 0);            // 41,943,040
  ushort* feat2 = (ushort*)(ws + 41943040);     // 25,165,824
  ushort* feat3 = (ushort*)(ws + 67108864);     // 16,777,216
  ushort* feat4 = (ushort*)(ws + 83886080);     //  8,388,608
  float*  gibuf = (float*) (ws + 92274688);     // 50,331,648  [t][b][1536]
  float*  hsbuf = (float*) (ws + 142606336);    // 16,777,216  [t][b][512]
  ushort* w2b   = (ushort*)(ws + 159383552);    //    589,824
  ushort* fc1wb = (ushort*)(ws + 159973376);    //  3,145,728
  ushort* fc2wb = (ushort*)(ws + 163119104);    //  1,048,576
  ushort* wihb  = (ushort*)(ws + 164167680);    //  1,572,864
  unsigned* bar = (unsigned*)(ws + 165740544);  //         64

  // weight converts (fp32 -> bf16)
  f32_to_bf16<<<288, 256, 0, stream>>>(w2, w2b, 73728);
  f32_to_bf16<<<1536, 256, 0, stream>>>(fc1w, fc1wb, 393216);
  f32_to_bf16<<<512, 256, 0, stream>>>(fc2w, fc2wb, 131072);
  f32_to_bf16<<<768, 256, 0, stream>>>(wih, wihb, 196608);

  // conv1 + pool -> bf16
  conv1_kernel<<<8192, 256, 0, stream>>>(phone, w1, b1, out1b);
  // conv2 + pool: im2col GEMM M=98304 K=1152 N=256
  gemm_bf16<1, 1><<<dim3(768, 2), 256, 0, stream>>>(out1b, w2b, b2, feat2, 1152, 0, 0);
  // fc1: M=8192 K=1536 N=1024
  gemm_bf16<0, 0><<<dim3(64, 8), 256, 0, stream>>>(feat2, fc1wb, fc1b, feat3, 1536, 1536, 1024);
  // fc2: M=8192 K=1024 N=512
  gemm_bf16<0, 0><<<dim3(64, 4), 256, 0, stream>>>(feat3, fc2wb, fc2b, feat4, 1024, 1024, 512);
  // gi = feat @ Wih^T + bih -> fp32 [t][b][1536]
  gemm_bf16<0, 2><<<dim3(64, 12), 256, 0, stream>>>(feat4, wihb, bih, gibuf, 512, 512, 1536);

  // persistent GRU (single dispatch, internal grid barrier)
  hipMemsetAsync(bar, 0, 64, stream);
  gru_persistent<<<16, 384, 0, stream>>>(h0, gibuf, whh, bhh, hsbuf, bar);

  // fc3
  fc3_kernel<<<32, 256, 0, stream>>>(hsbuf, w3, b3, out);
}

// Round 3
// 2371.540 us; speedup vs baseline: 2.6705x; 1.2509x over previous
//
#include <hip/hip_runtime.h>
#include <hip/hip_bf16.h>
#include <math.h>
#include <stdint.h>

typedef __attribute__((ext_vector_type(8))) short short8;
typedef __attribute__((ext_vector_type(4))) float f32x4;

#define T_ 512

__device__ __forceinline__ unsigned short bf16rn(float f) {
  union { float f; unsigned u; } x; x.f = f;
  unsigned r = x.u + 0x7FFF + ((x.u >> 16) & 1);
  return (unsigned short)(r >> 16);
}

__device__ __forceinline__ void gload16(const void* gsrc, void* ldst) {
  __builtin_amdgcn_global_load_lds(
      (const __attribute__((address_space(1))) unsigned int*)gsrc,
      (__attribute__((address_space(3))) unsigned int*)ldst, 16, 0, 0);
}

// ---------------- conv1 + pool (fp32 math, bf16 out), 8 frames/block ----------------
__global__ __launch_bounds__(256) void conv1_kernel(
    const float* __restrict__ phone, const float* __restrict__ w1,
    const float* __restrict__ b1, ushort* __restrict__ out1b) {
  __shared__ float ws[128 * 77];
  __shared__ float bs[128];
  __shared__ float xs[8][7][52];
  const int tid = threadIdx.x;
  const int n0 = blockIdx.x * 8;
  for (int idx = tid; idx < 9856; idx += 256) ws[idx] = w1[idx];
  if (tid < 128) bs[tid] = b1[tid];
  for (int idx = tid; idx < 2800; idx += 256) {
    int fi = idx / 350, r = idx - fi * 350;
    int ll = r / 7, c = r - ll * 7;
    xs[fi][c][ll] = phone[(size_t)(n0 + fi) * 350 + r];
  }
  __syncthreads();

  const int o = tid >> 1, ph = tid & 1;
  const float* wo = ws + o * 77;
  const float bb = bs[o];
  for (int fi = 0; fi < 8; ++fi) {
    float acc0[10], acc1[10];
#pragma unroll
    for (int q = 0; q < 10; ++q) { acc0[q] = 0.f; acc1[q] = 0.f; }
    for (int i = 0; i < 7; ++i) {
      float wr[11];
#pragma unroll
      for (int k = 0; k < 11; ++k) wr[k] = wo[i * 11 + k];
#pragma unroll
      for (int q = 0; q < 10; ++q) {
        int p = ph * 10 + q;
        int base = 2 * p;
        float xv[12];
#pragma unroll
        for (int j = 0; j < 12; ++j) xv[j] = xs[fi][i][base + j];
        float s0 = 0.f, s1 = 0.f;
#pragma unroll
        for (int k = 0; k < 11; ++k) {
          s0 += xv[k] * wr[k];
          s1 += xv[k + 1] * wr[k];
        }
        acc0[q] += s0;
        acc1[q] += s1;
      }
    }
#pragma unroll
    for (int q = 0; q < 10; ++q) {
      int p = ph * 10 + q;
      out1b[((size_t)(n0 + fi) * 128 + o) * 20 + p] =
          bf16rn(fmaxf(acc0[q], acc1[q]) + bb);
    }
  }
}

// ---------------- fp32 -> bf16 convert ----------------
__global__ __launch_bounds__(256) void f32_to_bf16(
    const float* __restrict__ src, ushort* __restrict__ dst, int n4) {
  int i = blockIdx.x * 256 + threadIdx.x;
  if (i < n4) {
    float4 v = ((const float4*)src)[i];
    ushort4 o;
    o.x = bf16rn(v.x); o.y = bf16rn(v.y); o.z = bf16rn(v.z); o.w = bf16rn(v.w);
    ((ushort4*)dst)[i] = o;
  }
}

// ---------------- stage h0 -> bf16 A-fragments (parity-1 buffer) ----------------
__global__ __launch_bounds__(512) void stage_h0(
    const float* __restrict__ h0, ushort* __restrict__ hx) {
  const int tid = threadIdx.x;
#pragma unroll
  for (int q = 0; q < 4; ++q) {
    int i = tid + q * 512;             // 0..2047
    int b = i >> 7, k = (i & 127) * 4;
    float4 v = *(const float4*)(h0 + (size_t)b * 512 + k);
    int s = k >> 5, fq = (k >> 3) & 3, j0 = k & 7;
    int lane = b | (fq << 4);
    ushort4 u;
    u.x = bf16rn(v.x); u.y = bf16rn(v.y); u.z = bf16rn(v.z); u.w = bf16rn(v.w);
    *(ushort4*)(hx + 8192 + s * 512 + lane * 8 + j0) = u;
  }
}

// ---------------- bf16 MFMA GEMM: C = A @ W^T + bias ----------------
template <int AM, int EM>
__global__ __launch_bounds__(256) void gemm_bf16(
    const ushort* __restrict__ A, const ushort* __restrict__ W,
    const float* __restrict__ bias, void* __restrict__ Cout,
    int K, int lda, int ldc) {
  __shared__ ushort As[128 * 64];
  __shared__ ushort Bs[128 * 64];
  const int tid = threadIdx.x;
  const int l = tid & 63, wv = tid >> 6;
  const int wr = wv >> 1, wc = wv & 1;
  const int fr = l & 15, fq = l >> 4;
  const int bm0 = blockIdx.x * 128, bn0 = blockIdx.y * 128;

  f32x4 acc[4][4];
#pragma unroll
  for (int mi = 0; mi < 4; ++mi)
#pragma unroll
    for (int ni = 0; ni < 4; ++ni) acc[mi][ni] = (f32x4)0.f;

  const int pr8 = l >> 3;
  const int pc = l & 7;
  const int nkt = K >> 6;
  for (int kt = 0; kt < nkt; ++kt) {
    const int k0 = kt << 6;
#pragma unroll
    for (int i = 0; i < 4; ++i) {
      int q = wv * 4 + i;
      int prow = q * 8 + pr8;
      int lc = pc ^ (prow & 7);
      gload16(W + (size_t)(bn0 + prow) * K + k0 + lc * 8, &Bs[q * 512]);
    }
    if (AM == 0) {
#pragma unroll
      for (int i = 0; i < 4; ++i) {
        int q = wv * 4 + i;
        int prow = q * 8 + pr8;
        int lc = pc ^ (prow & 7);
        gload16(A + (size_t)(bm0 + prow) * lda + k0 + lc * 8, &As[q * 512]);
      }
    } else {
      // im2col gather, paired uint LDS writes
#pragma unroll
      for (int q = 0; q < 16; ++q) {
        int idx = tid + q * 256;        // 4096 pair items
        int row = idx >> 5, c0 = (idx & 31) * 2;
        int m = bm0 + row;
        int n = m / 12, pos = m - n * 12;
        int kk = k0 + c0;
        int i2 = kk / 9, kp = kk - i2 * 9;
        uint e0 = A[(size_t)n * 2560 + i2 * 20 + pos + kp];
        int kk1 = kk + 1;
        int i3 = kk1 / 9, kp1 = kk1 - i3 * 9;
        uint e1 = A[(size_t)n * 2560 + i3 * 20 + pos + kp1];
        *(uint*)&As[row * 64 + (((c0 >> 3) ^ (row & 7)) << 3) + (c0 & 7)] =
            e0 | (e1 << 16);
      }
    }
    __syncthreads();
#pragma unroll
    for (int ks = 0; ks < 2; ++ks) {
      short8 af[4], bfr[4];
#pragma unroll
      for (int mi = 0; mi < 4; ++mi) {
        int row = wr * 64 + mi * 16 + fr;
        af[mi] = *(const short8*)&As[row * 64 + (((ks * 4 + fq) ^ (row & 7)) << 3)];
      }
#pragma unroll
      for (int ni = 0; ni < 4; ++ni) {
        int row = wc * 64 + ni * 16 + fr;
        bfr[ni] = *(const short8*)&Bs[row * 64 + (((ks * 4 + fq) ^ (row & 7)) << 3)];
      }
#pragma unroll
      for (int mi = 0; mi < 4; ++mi)
#pragma unroll
        for (int ni = 0; ni < 4; ++ni)
          acc[mi][ni] = __builtin_amdgcn_mfma_f32_16x16x32_bf16(
              af[mi], bfr[ni], acc[mi][ni], 0, 0, 0);
    }
    __syncthreads();
  }

#pragma unroll
  for (int ni = 0; ni < 4; ++ni) {
    int col = bn0 + wc * 64 + ni * 16 + fr;
    float bv = bias[col];
#pragma unroll
    for (int mi = 0; mi < 4; ++mi) {
      int mbase = bm0 + wr * 64 + mi * 16 + fq * 4;
      if (EM == 0) {
        ushort* C = (ushort*)Cout;
#pragma unroll
        for (int j = 0; j < 4; ++j)
          C[(size_t)(mbase + j) * ldc + col] = bf16rn(acc[mi][ni][j] + bv);
      } else if (EM == 1) {
        ushort* C = (ushort*)Cout;
#pragma unroll
        for (int j = 0; j < 4; j += 2) {
          int m = mbase + j;
          int n = m / 12, pos = m - n * 12;
          float v = fmaxf(acc[mi][ni][j], acc[mi][ni][j + 1]) + bv;
          C[(size_t)n * 1536 + col * 6 + (pos >> 1)] = bf16rn(v);
        }
      } else {
        float* C = (float*)Cout;
#pragma unroll
        for (int j = 0; j < 4; ++j) {
          int m = mbase + j;
          int b = m >> 9, tt = m & 511;
          C[((size_t)tt * 16 + b) * 1536 + col] = acc[mi][ni][j] + bv;
        }
      }
    }
  }
}

// ---------------- persistent GRU: 16 WGs, per-producer flags ----------------
// WG w owns h-dims [w*32, w*32+32) for all 3 gates (96 MFMA rows = 6 waves).
// h exchanged as bf16 A-fragments: fragment s=w is the WG's 1KB slice.
// fp32 h state lives in gate-thread registers; gi prefetched one step ahead.
__global__ __launch_bounds__(384) void gru_persistent(
    const float* __restrict__ h0, const float* __restrict__ gi,
    const float* __restrict__ whh, const float* __restrict__ bhh,
    float* __restrict__ hsbuf, ushort* __restrict__ hx,
    unsigned* __restrict__ flags) {
  __shared__ float gh_lds[6 * 256];
  const int tid = threadIdx.x;
  const int w = blockIdx.x;              // 0..15
  const int l = tid & 63, v = tid >> 6;  // wave 0..5
  const int fr = l & 15, fq = l >> 4;
  const int g = v >> 1, half = v & 1;
  const int o = g * 512 + w * 32 + half * 16 + fr;

  // persistent Whh B-fragments (64 VGPR)
  short8 bfrag[16];
#pragma unroll
  for (int s = 0; s < 16; ++s) {
    const float* wp = whh + (size_t)o * 512 + s * 32 + fq * 8;
    float4 w0 = *(const float4*)wp;
    float4 w1 = *(const float4*)(wp + 4);
    short8 bb;
    bb[0] = (short)bf16rn(w0.x); bb[1] = (short)bf16rn(w0.y);
    bb[2] = (short)bf16rn(w0.z); bb[3] = (short)bf16rn(w0.w);
    bb[4] = (short)bf16rn(w1.x); bb[5] = (short)bf16rn(w1.y);
    bb[6] = (short)bf16rn(w1.z); bb[7] = (short)bf16rn(w1.w);
    bfrag[s] = bb;
  }
  const float bo = bhh[o];

  // gate-thread persistent state (threads 0..255): pair (jl, jl+1)
  const int b = tid >> 4, jp = tid & 15, jl = jp * 2;
  const bool gthr = (tid < 256);
  float hA = 0.f, hB = 0.f;
  float giA0 = 0.f, giA1 = 0.f, giA2 = 0.f, giB0 = 0.f, giB1 = 0.f, giB2 = 0.f;
  if (gthr) {
    float2 h2 = *(const float2*)(h0 + (size_t)b * 512 + w * 32 + jl);
    hA = h2.x; hB = h2.y;
    const float* gb = gi + (size_t)b * 1536 + w * 32 + jl;  // t = 0
    float2 r0 = *(const float2*)(gb);
    float2 r1 = *(const float2*)(gb + 512);
    float2 r2 = *(const float2*)(gb + 1024);
    giA0 = r0.x; giB0 = r0.y; giA1 = r1.x; giB1 = r1.y; giA2 = r2.x; giB2 = r2.y;
  }

  for (int t = 0; t < T_; ++t) {
    // wait for all other producers' h_{t-1}
    if (t > 0) {
      bool ok;
      do {
        unsigned f = 0xFFFFFFFFu;
        if (l < 16 && l != w)
          f = __hip_atomic_load(flags + l * 32, __ATOMIC_RELAXED,
                                __HIP_MEMORY_SCOPE_AGENT);
        ok = __all((int)(f >= (unsigned)t));
      } while (!ok);
      __builtin_amdgcn_fence(__ATOMIC_ACQUIRE, "agent");
    }
    // load h_{t-1} fragments straight to VGPRs; 2-chain MFMA
    const ushort* hxp = hx + (((t + 1) & 1) << 13);
    short8 af[16];
#pragma unroll
    for (int s = 0; s < 16; ++s)
      af[s] = *(const short8*)(hxp + s * 512 + l * 8);
    f32x4 a0 = (f32x4)0.f, a1 = (f32x4)0.f;
#pragma unroll
    for (int s = 0; s < 8; ++s) {
      a0 = __builtin_amdgcn_mfma_f32_16x16x32_bf16(af[2 * s], bfrag[2 * s], a0, 0, 0, 0);
      a1 = __builtin_amdgcn_mfma_f32_16x16x32_bf16(af[2 * s + 1], bfrag[2 * s + 1], a1, 0, 0, 0);
    }
#pragma unroll
    for (int j = 0; j < 4; ++j)
      gh_lds[v * 256 + (fq * 4 + j) * 16 + fr] = a0[j] + a1[j] + bo;
    __syncthreads();

    if (gthr) {
      const int hh = jl >> 4, c = jl & 15;
      float2 rr = *(const float2*)&gh_lds[(0 + hh) * 256 + b * 16 + c];
      float2 zz = *(const float2*)&gh_lds[(2 + hh) * 256 + b * 16 + c];
      float2 nn = *(const float2*)&gh_lds[(4 + hh) * 256 + b * 16 + c];
      float rgA = 1.f / (1.f + __expf(-(giA0 + rr.x)));
      float rgB = 1.f / (1.f + __expf(-(giB0 + rr.y)));
      float zgA = 1.f / (1.f + __expf(-(giA1 + zz.x)));
      float zgB = 1.f / (1.f + __expf(-(giB1 + zz.y)));
      float ngA = tanhf(giA2 + rgA * nn.x);
      float ngB = tanhf(giB2 + rgB * nn.y);
      hA = (1.f - zgA) * ngA + zgA * hA;
      hB = (1.f - zgB) * ngB + zgB * hB;
      // fp32 for fc3 (fire-and-forget)
      *(float2*)(hsbuf + ((size_t)t * 16 + b) * 512 + w * 32 + jl) =
          make_float2(hA, hB);
      // bf16 fragment pair for consumers
      uint pk = (uint)bf16rn(hA) | ((uint)bf16rn(hB) << 16);
      ushort* dst = hx + ((t & 1) << 13) + w * 512 + (b | ((jl >> 3) << 4)) * 8 + (jl & 7);
      *(uint*)dst = pk;
      // prefetch gi for t+1 (latency hidden under release + next poll)
      if (t + 1 < T_) {
        const float* gb = gi + ((size_t)(t + 1) * 16 + b) * 1536 + w * 32 + jl;
        float2 r0 = *(const float2*)(gb);
        float2 r1 = *(const float2*)(gb + 512);
        float2 r2 = *(const float2*)(gb + 1024);
        giA0 = r0.x; giB0 = r0.y; giA1 = r1.x; giB1 = r1.y; giA2 = r2.x; giB2 = r2.y;
      }
    }
    if (t + 1 < T_) {
      __syncthreads();  // all hx stores drained (implies vmcnt(0))
      if (tid == 0)
        __hip_atomic_store(flags + w * 32, (unsigned)(t + 1), __ATOMIC_RELEASE,
                           __HIP_MEMORY_SCOPE_AGENT);
    }
  }
}

// ---------------- fc3 ----------------
__global__ __launch_bounds__(256) void fc3_kernel(
    const float* __restrict__ hs, const float* __restrict__ w3,
    const float* __restrict__ b3, float* __restrict__ out) {
  __shared__ float w[512];
  const int tid = threadIdx.x;
  w[tid] = w3[tid];
  w[tid + 256] = w3[tid + 256];
  __syncthreads();
  const int gidx = blockIdx.x * 256 + tid;  // b*512 + t
  const int b = gidx >> 9, t = gidx & 511;
  const float4* hr = (const float4*)(hs + ((size_t)t * 16 + b) * 512);
  const float4* wr = (const float4*)w;
  float acc = 0.f;
#pragma unroll 8
  for (int kc = 0; kc < 128; ++kc) {
    float4 h = hr[kc], ww = wr[kc];
    acc += h.x * ww.x + h.y * ww.y + h.z * ww.z + h.w * ww.w;
  }
  out[gidx] = acc + b3[0];
}

// ---------------------------------------------------------------------------
extern "C" void kernel_launch(void* const* d_in, const int* in_sizes, int n_in,
                              void* d_out, int out_size, void* d_ws,
                              size_t ws_size, hipStream_t stream) {
  const float* phone = (const float*)d_in[0];
  const float* h0    = (const float*)d_in[1];
  const float* w1    = (const float*)d_in[2];
  const float* b1    = (const float*)d_in[3];
  const float* w2    = (const float*)d_in[4];
  const float* b2    = (const float*)d_in[5];
  const float* fc1w  = (const float*)d_in[6];
  const float* fc1b  = (const float*)d_in[7];
  const float* fc2w  = (const float*)d_in[8];
  const float* fc2b  = (const float*)d_in[9];
  const float* wih   = (const float*)d_in[10];
  const float* whh   = (const float*)d_in[11];
  const float* bih   = (const float*)d_in[12];
  const float* bhh   = (const float*)d_in[13];
  const float* w3    = (const float*)d_in[14];
  const float* b3    = (const float*)d_in[15];
  float* out = (float*)d_out;

  char* ws = (char*)d_ws;
  ushort* out1b = (ushort*)(ws + 0);            // 41,943,040
  ushort* feat2 = (ushort*)(ws + 41943040);     // 25,165,824
  ushort* feat3 = (ushort*)(ws + 67108864);     // 16,777,216 (dead after fc2)
  ushort* feat4 = (ushort*)(ws + 83886080);     //  8,388,608
  float*  gibuf = (float*) (ws + 92274688);     // 50,331,648  [t][b][1536]
  float*  hsbuf = (float*) (ws + 142606336);    // 16,777,216  [t][b][512]
  ushort* w2b   = (ushort*)(ws + 159383552);    //    589,824
  ushort* fc1wb = (ushort*)(ws + 159973376);    //  3,145,728
  ushort* fc2wb = (ushort*)(ws + 163119104);    //  1,048,576
  ushort* wihb  = (ushort*)(ws + 164167680);    //  1,572,864
  // hx + flags overlap the dead feat3 region (written only after fc2 ran)
  ushort*   hx    = (ushort*)(ws + 67108864);   // 32,768 (2 x 16KB parity)
  unsigned* flags = (unsigned*)(ws + 67141632); // 2,048 (16 x 128B)

  f32_to_bf16<<<288, 256, 0, stream>>>(w2, w2b, 73728);
  f32_to_bf16<<<1536, 256, 0, stream>>>(fc1w, fc1wb, 393216);
  f32_to_bf16<<<512, 256, 0, stream>>>(fc2w, fc2wb, 131072);
  f32_to_bf16<<<768, 256, 0, stream>>>(wih, wihb, 196608);

  conv1_kernel<<<1024, 256, 0, stream>>>(phone, w1, b1, out1b);
  gemm_bf16<1, 1><<<dim3(768, 2), 256, 0, stream>>>(out1b, w2b, b2, feat2, 1152, 0, 0);
  gemm_bf16<0, 0><<<dim3(64, 8), 256, 0, stream>>>(feat2, fc1wb, fc1b, feat3, 1536, 1536, 1024);
  gemm_bf16<0, 0><<<dim3(64, 4), 256, 0, stream>>>(feat3, fc2wb, fc2b, feat4, 1024, 1024, 512);
  gemm_bf16<0, 2><<<dim3(64, 12), 256, 0, stream>>>(feat4, wihb, bih, gibuf, 512, 512, 1536);

  hipMemsetAsync(flags, 0, 2048, stream);
  stage_h0<<<1, 512, 0, stream>>>(h0, hx);
  gru_persistent<<<16, 384, 0, stream>>>(h0, gibuf, whh, bhh, hsbuf, hx, flags);

  fc3_kernel<<<32, 256, 0, stream>>>(hsbuf, w3, b3, out);
}

// Round 4
// 2336.345 us; speedup vs baseline: 2.7108x; 1.0151x over previous
//
#include <hip/hip_runtime.h>
#include <hip/hip_bf16.h>
#include <math.h>
#include <stdint.h>

typedef __attribute__((ext_vector_type(8))) short short8;
typedef __attribute__((ext_vector_type(4))) float f32x4;

#define T_ 512

__device__ __forceinline__ unsigned short bf16rn(float f) {
  union { float f; unsigned u; } x; x.f = f;
  unsigned r = x.u + 0x7FFF + ((x.u >> 16) & 1);
  return (unsigned short)(r >> 16);
}

__device__ __forceinline__ void gload16(const void* gsrc, void* ldst) {
  __builtin_amdgcn_global_load_lds(
      (const __attribute__((address_space(1))) unsigned int*)gsrc,
      (__attribute__((address_space(3))) unsigned int*)ldst, 16, 0, 0);
}

// ---------------- conv1 + pool (fp32 math, bf16 out), 8 frames/block ----------------
__global__ __launch_bounds__(256) void conv1_kernel(
    const float* __restrict__ phone, const float* __restrict__ w1,
    const float* __restrict__ b1, ushort* __restrict__ out1b) {
  __shared__ float ws[128 * 77];
  __shared__ float bs[128];
  __shared__ float xs[8][7][52];
  const int tid = threadIdx.x;
  const int n0 = blockIdx.x * 8;
  for (int idx = tid; idx < 9856; idx += 256) ws[idx] = w1[idx];
  if (tid < 128) bs[tid] = b1[tid];
  for (int idx = tid; idx < 2800; idx += 256) {
    int fi = idx / 350, r = idx - fi * 350;
    int ll = r / 7, c = r - ll * 7;
    xs[fi][c][ll] = phone[(size_t)(n0 + fi) * 350 + r];
  }
  __syncthreads();

  const int o = tid >> 1, ph = tid & 1;
  const float* wo = ws + o * 77;
  const float bb = bs[o];
  for (int fi = 0; fi < 8; ++fi) {
    float acc0[10], acc1[10];
#pragma unroll
    for (int q = 0; q < 10; ++q) { acc0[q] = 0.f; acc1[q] = 0.f; }
    for (int i = 0; i < 7; ++i) {
      float wr[11];
#pragma unroll
      for (int k = 0; k < 11; ++k) wr[k] = wo[i * 11 + k];
#pragma unroll
      for (int q = 0; q < 10; ++q) {
        int p = ph * 10 + q;
        int base = 2 * p;
        float xv[12];
#pragma unroll
        for (int j = 0; j < 12; ++j) xv[j] = xs[fi][i][base + j];
        float s0 = 0.f, s1 = 0.f;
#pragma unroll
        for (int k = 0; k < 11; ++k) {
          s0 += xv[k] * wr[k];
          s1 += xv[k + 1] * wr[k];
        }
        acc0[q] += s0;
        acc1[q] += s1;
      }
    }
#pragma unroll
    for (int q = 0; q < 10; ++q) {
      int p = ph * 10 + q;
      out1b[((size_t)(n0 + fi) * 128 + o) * 20 + p] =
          bf16rn(fmaxf(acc0[q], acc1[q]) + bb);
    }
  }
}

// ---------------- fp32 -> bf16 convert ----------------
__global__ __launch_bounds__(256) void f32_to_bf16(
    const float* __restrict__ src, ushort* __restrict__ dst, int n4) {
  int i = blockIdx.x * 256 + threadIdx.x;
  if (i < n4) {
    float4 v = ((const float4*)src)[i];
    ushort4 o;
    o.x = bf16rn(v.x); o.y = bf16rn(v.y); o.z = bf16rn(v.z); o.w = bf16rn(v.w);
    ((ushort4*)dst)[i] = o;
  }
}

// ---------------- stage h0 -> bf16 A-fragments (parity-1 buffer) ----------------
__global__ __launch_bounds__(512) void stage_h0(
    const float* __restrict__ h0, ushort* __restrict__ hx) {
  const int tid = threadIdx.x;
#pragma unroll
  for (int q = 0; q < 4; ++q) {
    int i = tid + q * 512;             // 0..2047
    int b = i >> 7, k = (i & 127) * 4;
    float4 v = *(const float4*)(h0 + (size_t)b * 512 + k);
    int s = k >> 5, fq = (k >> 3) & 3, j0 = k & 7;
    int lane = b | (fq << 4);
    ushort4 u;
    u.x = bf16rn(v.x); u.y = bf16rn(v.y); u.z = bf16rn(v.z); u.w = bf16rn(v.w);
    *(ushort4*)(hx + 8192 + s * 512 + lane * 8 + j0) = u;
  }
}

// ---------------- bf16 MFMA GEMM: C = A @ W^T + bias ----------------
template <int AM, int EM>
__global__ __launch_bounds__(256) void gemm_bf16(
    const ushort* __restrict__ A, const ushort* __restrict__ W,
    const float* __restrict__ bias, void* __restrict__ Cout,
    int K, int lda, int ldc) {
  __shared__ ushort As[128 * 64];
  __shared__ ushort Bs[128 * 64];
  const int tid = threadIdx.x;
  const int l = tid & 63, wv = tid >> 6;
  const int wr = wv >> 1, wc = wv & 1;
  const int fr = l & 15, fq = l >> 4;
  const int bm0 = blockIdx.x * 128, bn0 = blockIdx.y * 128;

  f32x4 acc[4][4];
#pragma unroll
  for (int mi = 0; mi < 4; ++mi)
#pragma unroll
    for (int ni = 0; ni < 4; ++ni) acc[mi][ni] = (f32x4)0.f;

  const int pr8 = l >> 3;
  const int pc = l & 7;
  const int nkt = K >> 6;
  for (int kt = 0; kt < nkt; ++kt) {
    const int k0 = kt << 6;
#pragma unroll
    for (int i = 0; i < 4; ++i) {
      int q = wv * 4 + i;
      int prow = q * 8 + pr8;
      int lc = pc ^ (prow & 7);
      gload16(W + (size_t)(bn0 + prow) * K + k0 + lc * 8, &Bs[q * 512]);
    }
    if (AM == 0) {
#pragma unroll
      for (int i = 0; i < 4; ++i) {
        int q = wv * 4 + i;
        int prow = q * 8 + pr8;
        int lc = pc ^ (prow & 7);
        gload16(A + (size_t)(bm0 + prow) * lda + k0 + lc * 8, &As[q * 512]);
      }
    } else {
      // im2col gather, paired uint LDS writes
#pragma unroll
      for (int q = 0; q < 16; ++q) {
        int idx = tid + q * 256;        // 4096 pair items
        int row = idx >> 5, c0 = (idx & 31) * 2;
        int m = bm0 + row;
        int n = m / 12, pos = m - n * 12;
        int kk = k0 + c0;
        int i2 = kk / 9, kp = kk - i2 * 9;
        uint e0 = A[(size_t)n * 2560 + i2 * 20 + pos + kp];
        int kk1 = kk + 1;
        int i3 = kk1 / 9, kp1 = kk1 - i3 * 9;
        uint e1 = A[(size_t)n * 2560 + i3 * 20 + pos + kp1];
        *(uint*)&As[row * 64 + (((c0 >> 3) ^ (row & 7)) << 3) + (c0 & 7)] =
            e0 | (e1 << 16);
      }
    }
    __syncthreads();
#pragma unroll
    for (int ks = 0; ks < 2; ++ks) {
      short8 af[4], bfr[4];
#pragma unroll
      for (int mi = 0; mi < 4; ++mi) {
        int row = wr * 64 + mi * 16 + fr;
        af[mi] = *(const short8*)&As[row * 64 + (((ks * 4 + fq) ^ (row & 7)) << 3)];
      }
#pragma unroll
      for (int ni = 0; ni < 4; ++ni) {
        int row = wc * 64 + ni * 16 + fr;
        bfr[ni] = *(const short8*)&Bs[row * 64 + (((ks * 4 + fq) ^ (row & 7)) << 3)];
      }
#pragma unroll
      for (int mi = 0; mi < 4; ++mi)
#pragma unroll
        for (int ni = 0; ni < 4; ++ni)
          acc[mi][ni] = __builtin_amdgcn_mfma_f32_16x16x32_bf16(
              af[mi], bfr[ni], acc[mi][ni], 0, 0, 0);
    }
    __syncthreads();
  }

#pragma unroll
  for (int ni = 0; ni < 4; ++ni) {
    int col = bn0 + wc * 64 + ni * 16 + fr;
    float bv = bias[col];
#pragma unroll
    for (int mi = 0; mi < 4; ++mi) {
      int mbase = bm0 + wr * 64 + mi * 16 + fq * 4;
      if (EM == 0) {
        ushort* C = (ushort*)Cout;
#pragma unroll
        for (int j = 0; j < 4; ++j)
          C[(size_t)(mbase + j) * ldc + col] = bf16rn(acc[mi][ni][j] + bv);
      } else if (EM == 1) {
        ushort* C = (ushort*)Cout;
#pragma unroll
        for (int j = 0; j < 4; j += 2) {
          int m = mbase + j;
          int n = m / 12, pos = m - n * 12;
          float v = fmaxf(acc[mi][ni][j], acc[mi][ni][j + 1]) + bv;
          C[(size_t)n * 1536 + col * 6 + (pos >> 1)] = bf16rn(v);
        }
      } else {
        float* C = (float*)Cout;
#pragma unroll
        for (int j = 0; j < 4; ++j) {
          int m = mbase + j;
          int b = m >> 9, tt = m & 511;
          C[((size_t)tt * 16 + b) * 1536 + col] = acc[mi][ni][j] + bv;
        }
      }
    }
  }
}

// ---------------- persistent GRU: 16 WGs, per-wave relaxed-coherent release ----------------
// WG w owns h-dims [w*32, w*32+32) for all 3 gates.  h exchanged as bf16
// A-fragments through LLC via relaxed agent-scope atomics (sc0/sc1): no
// fences, no producer-side barrier on the release path.  64 seq words =
// (WG w x gate-wave gw); consumer lane l polls seq[l].  hsbuf store + gi
// prefetch issued AFTER the seq release (off the critical path).
__global__ __launch_bounds__(384) void gru_persistent(
    const float* __restrict__ h0, const float* __restrict__ gi,
    const float* __restrict__ whh, const float* __restrict__ bhh,
    float* __restrict__ hsbuf, ushort* __restrict__ hx,
    unsigned* __restrict__ seq) {
  __shared__ float gh_lds[6 * 256];
  const int tid = threadIdx.x;
  const int w = blockIdx.x;              // 0..15
  const int l = tid & 63, v = tid >> 6;  // wave 0..5
  const int fr = l & 15, fq = l >> 4;
  const int g = v >> 1, half = v & 1;
  const int o = g * 512 + w * 32 + half * 16 + fr;

  // persistent Whh B-fragments (64 VGPR)
  short8 bfrag[16];
#pragma unroll
  for (int s = 0; s < 16; ++s) {
    const float* wp = whh + (size_t)o * 512 + s * 32 + fq * 8;
    float4 w0 = *(const float4*)wp;
    float4 w1 = *(const float4*)(wp + 4);
    short8 bb;
    bb[0] = (short)bf16rn(w0.x); bb[1] = (short)bf16rn(w0.y);
    bb[2] = (short)bf16rn(w0.z); bb[3] = (short)bf16rn(w0.w);
    bb[4] = (short)bf16rn(w1.x); bb[5] = (short)bf16rn(w1.y);
    bb[6] = (short)bf16rn(w1.z); bb[7] = (short)bf16rn(w1.w);
    bfrag[s] = bb;
  }
  const float bo = bhh[o];

  // gate-thread persistent state (threads 0..255): pair (jl, jl+1)
  const int b = tid >> 4, jp = tid & 15, jl = jp * 2;
  const bool gthr = (tid < 256);
  float hA = 0.f, hB = 0.f;
  float giA0 = 0.f, giA1 = 0.f, giA2 = 0.f, giB0 = 0.f, giB1 = 0.f, giB2 = 0.f;
  if (gthr) {
    float2 h2 = *(const float2*)(h0 + (size_t)b * 512 + w * 32 + jl);
    hA = h2.x; hB = h2.y;
    const float* gb = gi + (size_t)b * 1536 + w * 32 + jl;  // t = 0
    float2 r0 = *(const float2*)(gb);
    float2 r1 = *(const float2*)(gb + 512);
    float2 r2 = *(const float2*)(gb + 1024);
    giA0 = r0.x; giB0 = r0.y; giA1 = r1.x; giB1 = r1.y; giA2 = r2.x; giB2 = r2.y;
  }

  for (int t = 0; t < T_; ++t) {
    // wait: all 64 producer-wave seqs have completed step t-1
    if (t > 0) {
      unsigned f;
      do {
        f = __hip_atomic_load(seq + l * 32, __ATOMIC_RELAXED,
                              __HIP_MEMORY_SCOPE_AGENT);
      } while (!__all((int)(f >= (unsigned)t)));
      asm volatile("" ::: "memory");  // no fence needed: data loads below are coherent
    }
    // coherent-load h_{t-1} fragments straight to VGPRs
    const ushort* hxp = hx + (((t + 1) & 1) << 13);
    short8 af[16];
#pragma unroll
    for (int s = 0; s < 16; ++s) {
      const unsigned long long* p =
          (const unsigned long long*)(hxp + s * 512 + l * 8);
      unsigned long long lo = __hip_atomic_load(p, __ATOMIC_RELAXED,
                                                __HIP_MEMORY_SCOPE_AGENT);
      unsigned long long hi = __hip_atomic_load(p + 1, __ATOMIC_RELAXED,
                                                __HIP_MEMORY_SCOPE_AGENT);
      union { unsigned long long q[2]; short8 s8; } u;
      u.q[0] = lo; u.q[1] = hi;
      af[s] = u.s8;
    }
    // 4 independent MFMA chains of depth 4
    f32x4 a0 = (f32x4)0.f, a1 = (f32x4)0.f, a2 = (f32x4)0.f, a3 = (f32x4)0.f;
#pragma unroll
    for (int s = 0; s < 4; ++s) {
      a0 = __builtin_amdgcn_mfma_f32_16x16x32_bf16(af[4 * s + 0], bfrag[4 * s + 0], a0, 0, 0, 0);
      a1 = __builtin_amdgcn_mfma_f32_16x16x32_bf16(af[4 * s + 1], bfrag[4 * s + 1], a1, 0, 0, 0);
      a2 = __builtin_amdgcn_mfma_f32_16x16x32_bf16(af[4 * s + 2], bfrag[4 * s + 2], a2, 0, 0, 0);
      a3 = __builtin_amdgcn_mfma_f32_16x16x32_bf16(af[4 * s + 3], bfrag[4 * s + 3], a3, 0, 0, 0);
    }
#pragma unroll
    for (int j = 0; j < 4; ++j)
      gh_lds[v * 256 + (fq * 4 + j) * 16 + fr] = a0[j] + a1[j] + a2[j] + a3[j] + bo;
    __syncthreads();

    if (gthr) {
      const int hh = jl >> 4, c = jl & 15;
      float2 rr = *(const float2*)&gh_lds[(0 + hh) * 256 + b * 16 + c];
      float2 zz = *(const float2*)&gh_lds[(2 + hh) * 256 + b * 16 + c];
      float2 nn = *(const float2*)&gh_lds[(4 + hh) * 256 + b * 16 + c];
      float rgA = __builtin_amdgcn_rcpf(1.f + __expf(-(giA0 + rr.x)));
      float rgB = __builtin_amdgcn_rcpf(1.f + __expf(-(giB0 + rr.y)));
      float zgA = __builtin_amdgcn_rcpf(1.f + __expf(-(giA1 + zz.x)));
      float zgB = __builtin_amdgcn_rcpf(1.f + __expf(-(giB1 + zz.y)));
      float eA = __expf(2.f * (giA2 + rgA * nn.x));
      float eB = __expf(2.f * (giB2 + rgB * nn.y));
      float ngA = 1.f - 2.f * __builtin_amdgcn_rcpf(eA + 1.f);
      float ngB = 1.f - 2.f * __builtin_amdgcn_rcpf(eB + 1.f);
      hA = (1.f - zgA) * ngA + zgA * hA;
      hB = (1.f - zgB) * ngB + zgB * hB;
      // coherent bf16 fragment-pair store (straight to LLC)
      uint pk = (uint)bf16rn(hA) | ((uint)bf16rn(hB) << 16);
      unsigned* dst = (unsigned*)(hx + ((t & 1) << 13) + w * 512 +
                                  (b | ((jl >> 3) << 4)) * 8 + (jl & 7));
      __hip_atomic_store(dst, pk, __ATOMIC_RELAXED, __HIP_MEMORY_SCOPE_AGENT);
      // wave-local drain: this wave's hx stores are at the coherence point
      asm volatile("s_waitcnt vmcnt(0)" ::: "memory");
      if ((tid & 63) == 0)
        __hip_atomic_store(seq + (w * 4 + (tid >> 6)) * 32, (unsigned)(t + 1),
                           __ATOMIC_RELAXED, __HIP_MEMORY_SCOPE_AGENT);
      // off-critical-path: fp32 state for fc3, gi prefetch for t+1
      *(float2*)(hsbuf + ((size_t)t * 16 + b) * 512 + w * 32 + jl) =
          make_float2(hA, hB);
      if (t + 1 < T_) {
        const float* gb = gi + ((size_t)(t + 1) * 16 + b) * 1536 + w * 32 + jl;
        float2 r0 = *(const float2*)(gb);
        float2 r1 = *(const float2*)(gb + 512);
        float2 r2 = *(const float2*)(gb + 1024);
        giA0 = r0.x; giB0 = r0.y; giA1 = r1.x; giB1 = r1.y; giA2 = r2.x; giB2 = r2.y;
      }
    }
  }
}

// ---------------- fc3 ----------------
__global__ __launch_bounds__(256) void fc3_kernel(
    const float* __restrict__ hs, const float* __restrict__ w3,
    const float* __restrict__ b3, float* __restrict__ out) {
  __shared__ float w[512];
  const int tid = threadIdx.x;
  w[tid] = w3[tid];
  w[tid + 256] = w3[tid + 256];
  __syncthreads();
  const int gidx = blockIdx.x * 256 + tid;  // b*512 + t
  const int b = gidx >> 9, t = gidx & 511;
  const float4* hr = (const float4*)(hs + ((size_t)t * 16 + b) * 512);
  const float4* wr = (const float4*)w;
  float acc = 0.f;
#pragma unroll 8
  for (int kc = 0; kc < 128; ++kc) {
    float4 h = hr[kc], ww = wr[kc];
    acc += h.x * ww.x + h.y * ww.y + h.z * ww.z + h.w * ww.w;
  }
  out[gidx] = acc + b3[0];
}

// ---------------------------------------------------------------------------
extern "C" void kernel_launch(void* const* d_in, const int* in_sizes, int n_in,
                              void* d_out, int out_size, void* d_ws,
                              size_t ws_size, hipStream_t stream) {
  const float* phone = (const float*)d_in[0];
  const float* h0    = (const float*)d_in[1];
  const float* w1    = (const float*)d_in[2];
  const float* b1    = (const float*)d_in[3];
  const float* w2    = (const float*)d_in[4];
  const float* b2    = (const float*)d_in[5];
  const float* fc1w  = (const float*)d_in[6];
  const float* fc1b  = (const float*)d_in[7];
  const float* fc2w  = (const float*)d_in[8];
  const float* fc2b  = (const float*)d_in[9];
  const float* wih   = (const float*)d_in[10];
  const float* whh   = (const float*)d_in[11];
  const float* bih   = (const float*)d_in[12];
  const float* bhh   = (const float*)d_in[13];
  const float* w3    = (const float*)d_in[14];
  const float* b3    = (const float*)d_in[15];
  float* out = (float*)d_out;

  char* ws = (char*)d_ws;
  ushort* out1b = (ushort*)(ws + 0);            // 41,943,040
  ushort* feat2 = (ushort*)(ws + 41943040);     // 25,165,824
  ushort* feat3 = (ushort*)(ws + 67108864);     // 16,777,216 (dead after fc2)
  ushort* feat4 = (ushort*)(ws + 83886080);     //  8,388,608
  float*  gibuf = (float*) (ws + 92274688);     // 50,331,648  [t][b][1536]
  float*  hsbuf = (float*) (ws + 142606336);    // 16,777,216  [t][b][512]
  ushort* w2b   = (ushort*)(ws + 159383552);    //    589,824
  ushort* fc1wb = (ushort*)(ws + 159973376);    //  3,145,728
  ushort* fc2wb = (ushort*)(ws + 163119104);    //  1,048,576
  ushort* wihb  = (ushort*)(ws + 164167680);    //  1,572,864
  // hx + seq overlap the dead feat3 region (written only after fc2 ran)
  ushort*   hx  = (ushort*)(ws + 67108864);     // 32,768 (2 x 16KB parity)
  unsigned* seq = (unsigned*)(ws + 67141632);   // 8,192 (64 x 128B)

  f32_to_bf16<<<288, 256, 0, stream>>>(w2, w2b, 73728);
  f32_to_bf16<<<1536, 256, 0, stream>>>(fc1w, fc1wb, 393216);
  f32_to_bf16<<<512, 256, 0, stream>>>(fc2w, fc2wb, 131072);
  f32_to_bf16<<<768, 256, 0, stream>>>(wih, wihb, 196608);

  conv1_kernel<<<1024, 256, 0, stream>>>(phone, w1, b1, out1b);
  gemm_bf16<1, 1><<<dim3(768, 2), 256, 0, stream>>>(out1b, w2b, b2, feat2, 1152, 0, 0);
  gemm_bf16<0, 0><<<dim3(64, 8), 256, 0, stream>>>(feat2, fc1wb, fc1b, feat3, 1536, 1536, 1024);
  gemm_bf16<0, 0><<<dim3(64, 4), 256, 0, stream>>>(feat3, fc2wb, fc2b, feat4, 1024, 1024, 512);
  gemm_bf16<0, 2><<<dim3(64, 12), 256, 0, stream>>>(feat4, wihb, bih, gibuf, 512, 512, 1536);

  hipMemsetAsync(seq, 0, 8192, stream);
  stage_h0<<<1, 512, 0, stream>>>(h0, hx);
  gru_persistent<<<16, 384, 0, stream>>>(h0, gibuf, whh, bhh, hsbuf, hx, seq);

  fc3_kernel<<<32, 256, 0, stream>>>(hsbuf, w3, b3, out);
}

// Round 5
// 1838.299 us; speedup vs baseline: 3.4452x; 1.2709x over previous
//
#include <hip/hip_runtime.h>
#include <hip/hip_bf16.h>
#include <math.h>
#include <stdint.h>

typedef __attribute__((ext_vector_type(8))) short short8;
typedef __attribute__((ext_vector_type(4))) float f32x4;
typedef __attribute__((ext_vector_type(4))) unsigned int uint4v;

#define T_ 512

__device__ __forceinline__ unsigned short bf16rn(float f) {
  union { float f; unsigned u; } x; x.f = f;
  unsigned r = x.u + 0x7FFF + ((x.u >> 16) & 1);
  return (unsigned short)(r >> 16);
}

__device__ __forceinline__ void gload16(const void* gsrc, void* ldst) {
  __builtin_amdgcn_global_load_lds(
      (const __attribute__((address_space(1))) unsigned int*)gsrc,
      (__attribute__((address_space(3))) unsigned int*)ldst, 16, 0, 0);
}

// ---------------- conv1 + pool (fp32 math, bf16 out), 8 frames/block ----------------
__global__ __launch_bounds__(256) void conv1_kernel(
    const float* __restrict__ phone, const float* __restrict__ w1,
    const float* __restrict__ b1, ushort* __restrict__ out1b) {
  __shared__ float ws[128 * 77];
  __shared__ float bs[128];
  __shared__ float xs[8][7][52];
  const int tid = threadIdx.x;
  const int n0 = blockIdx.x * 8;
  for (int idx = tid; idx < 9856; idx += 256) ws[idx] = w1[idx];
  if (tid < 128) bs[tid] = b1[tid];
  for (int idx = tid; idx < 2800; idx += 256) {
    int fi = idx / 350, r = idx - fi * 350;
    int ll = r / 7, c = r - ll * 7;
    xs[fi][c][ll] = phone[(size_t)(n0 + fi) * 350 + r];
  }
  __syncthreads();

  const int o = tid >> 1, ph = tid & 1;
  const float* wo = ws + o * 77;
  const float bb = bs[o];
  for (int fi = 0; fi < 8; ++fi) {
    float acc0[10], acc1[10];
#pragma unroll
    for (int q = 0; q < 10; ++q) { acc0[q] = 0.f; acc1[q] = 0.f; }
    for (int i = 0; i < 7; ++i) {
      float wr[11];
#pragma unroll
      for (int k = 0; k < 11; ++k) wr[k] = wo[i * 11 + k];
#pragma unroll
      for (int q = 0; q < 10; ++q) {
        int p = ph * 10 + q;
        int base = 2 * p;
        float xv[12];
#pragma unroll
        for (int j = 0; j < 12; ++j) xv[j] = xs[fi][i][base + j];
        float s0 = 0.f, s1 = 0.f;
#pragma unroll
        for (int k = 0; k < 11; ++k) {
          s0 += xv[k] * wr[k];
          s1 += xv[k + 1] * wr[k];
        }
        acc0[q] += s0;
        acc1[q] += s1;
      }
    }
#pragma unroll
    for (int q = 0; q < 10; ++q) {
      int p = ph * 10 + q;
      out1b[((size_t)(n0 + fi) * 128 + o) * 20 + p] =
          bf16rn(fmaxf(acc0[q], acc1[q]) + bb);
    }
  }
}

// ---------------- fp32 -> bf16 convert ----------------
__global__ __launch_bounds__(256) void f32_to_bf16(
    const float* __restrict__ src, ushort* __restrict__ dst, int n4) {
  int i = blockIdx.x * 256 + threadIdx.x;
  if (i < n4) {
    float4 v = ((const float4*)src)[i];
    ushort4 o;
    o.x = bf16rn(v.x); o.y = bf16rn(v.y); o.z = bf16rn(v.z); o.w = bf16rn(v.w);
    ((ushort4*)dst)[i] = o;
  }
}

// ---------------- stage h0 -> tagged bf16 fragments (parity-0 buffer, tag 0) ----------------
__global__ __launch_bounds__(256) void stage_h0(
    const float* __restrict__ h0, unsigned long long* __restrict__ hxt) {
  const int tid = threadIdx.x;
  const int b = tid >> 4, x = tid & 15;
#pragma unroll
  for (int q = 0; q < 16; ++q) {
    int d = (x + q * 16) * 2;
    int s = d >> 5, fqq = (d >> 3) & 3, k = (d & 7) >> 1;
    int lane = b | (fqq << 4);
    float2 h2 = *(const float2*)(h0 + (size_t)b * 512 + d);
    unsigned pk = (unsigned)bf16rn(h2.x) | ((unsigned)bf16rn(h2.y) << 16);
    hxt[((size_t)s * 64 + lane) * 4 + k] = (unsigned long long)pk;  // tag = 0
  }
}

// ---------------- bf16 MFMA GEMM: C = A @ W^T + bias ----------------
template <int AM, int EM>
__global__ __launch_bounds__(256) void gemm_bf16(
    const ushort* __restrict__ A, const ushort* __restrict__ W,
    const float* __restrict__ bias, void* __restrict__ Cout,
    int K, int lda, int ldc) {
  __shared__ ushort As[128 * 64];
  __shared__ ushort Bs[128 * 64];
  const int tid = threadIdx.x;
  const int l = tid & 63, wv = tid >> 6;
  const int wr = wv >> 1, wc = wv & 1;
  const int fr = l & 15, fq = l >> 4;
  const int bm0 = blockIdx.x * 128, bn0 = blockIdx.y * 128;

  f32x4 acc[4][4];
#pragma unroll
  for (int mi = 0; mi < 4; ++mi)
#pragma unroll
    for (int ni = 0; ni < 4; ++ni) acc[mi][ni] = (f32x4)0.f;

  const int pr8 = l >> 3;
  const int pc = l & 7;
  const int nkt = K >> 6;
  for (int kt = 0; kt < nkt; ++kt) {
    const int k0 = kt << 6;
#pragma unroll
    for (int i = 0; i < 4; ++i) {
      int q = wv * 4 + i;
      int prow = q * 8 + pr8;
      int lc = pc ^ (prow & 7);
      gload16(W + (size_t)(bn0 + prow) * K + k0 + lc * 8, &Bs[q * 512]);
    }
    if (AM == 0) {
#pragma unroll
      for (int i = 0; i < 4; ++i) {
        int q = wv * 4 + i;
        int prow = q * 8 + pr8;
        int lc = pc ^ (prow & 7);
        gload16(A + (size_t)(bm0 + prow) * lda + k0 + lc * 8, &As[q * 512]);
      }
    } else {
      // im2col gather, paired uint LDS writes
#pragma unroll
      for (int q = 0; q < 16; ++q) {
        int idx = tid + q * 256;        // 4096 pair items
        int row = idx >> 5, c0 = (idx & 31) * 2;
        int m = bm0 + row;
        int n = m / 12, pos = m - n * 12;
        int kk = k0 + c0;
        int i2 = kk / 9, kp = kk - i2 * 9;
        uint e0 = A[(size_t)n * 2560 + i2 * 20 + pos + kp];
        int kk1 = kk + 1;
        int i3 = kk1 / 9, kp1 = kk1 - i3 * 9;
        uint e1 = A[(size_t)n * 2560 + i3 * 20 + pos + kp1];
        *(uint*)&As[row * 64 + (((c0 >> 3) ^ (row & 7)) << 3) + (c0 & 7)] =
            e0 | (e1 << 16);
      }
    }
    __syncthreads();
#pragma unroll
    for (int ks = 0; ks < 2; ++ks) {
      short8 af[4], bfr[4];
#pragma unroll
      for (int mi = 0; mi < 4; ++mi) {
        int row = wr * 64 + mi * 16 + fr;
        af[mi] = *(const short8*)&As[row * 64 + (((ks * 4 + fq) ^ (row & 7)) << 3)];
      }
#pragma unroll
      for (int ni = 0; ni < 4; ++ni) {
        int row = wc * 64 + ni * 16 + fr;
        bfr[ni] = *(const short8*)&Bs[row * 64 + (((ks * 4 + fq) ^ (row & 7)) << 3)];
      }
#pragma unroll
      for (int mi = 0; mi < 4; ++mi)
#pragma unroll
        for (int ni = 0; ni < 4; ++ni)
          acc[mi][ni] = __builtin_amdgcn_mfma_f32_16x16x32_bf16(
              af[mi], bfr[ni], acc[mi][ni], 0, 0, 0);
    }
    __syncthreads();
  }

#pragma unroll
  for (int ni = 0; ni < 4; ++ni) {
    int col = bn0 + wc * 64 + ni * 16 + fr;
    float bv = bias[col];
#pragma unroll
    for (int mi = 0; mi < 4; ++mi) {
      int mbase = bm0 + wr * 64 + mi * 16 + fq * 4;
      if (EM == 0) {
        ushort* C = (ushort*)Cout;
#pragma unroll
        for (int j = 0; j < 4; ++j)
          C[(size_t)(mbase + j) * ldc + col] = bf16rn(acc[mi][ni][j] + bv);
      } else if (EM == 1) {
        ushort* C = (ushort*)Cout;
#pragma unroll
        for (int j = 0; j < 4; j += 2) {
          int m = mbase + j;
          int n = m / 12, pos = m - n * 12;
          float v = fmaxf(acc[mi][ni][j], acc[mi][ni][j + 1]) + bv;
          C[(size_t)n * 1536 + col * 6 + (pos >> 1)] = bf16rn(v);
        }
      } else {
        float* C = (float*)Cout;
#pragma unroll
        for (int j = 0; j < 4; ++j) {
          int m = mbase + j;
          int b = m >> 9, tt = m & 511;
          C[((size_t)tt * 16 + b) * 1536 + col] = acc[mi][ni][j] + bv;
        }
      }
    }
  }
}

// ---------------- persistent GRU: tagged single-store exchange ----------------
// h exchanged as {bf16-pair, step-tag} 8B words (2-parity buffers).  Producer:
// ONE relaxed agent-scope 8B store per pair (data+flag atomic together, no seq,
// no drain).  Consumer: 256 threads/WG cooperatively batch-load the 32KB tagged
// buffer (8x dwordx4 sc0 sc1 each, one vmcnt), tag-check, retry; deposit into
// LDS once; all 6 waves read fragments from LDS.
__global__ __launch_bounds__(384) void gru_persistent(
    const float* __restrict__ h0, const float* __restrict__ gi,
    const float* __restrict__ whh, const float* __restrict__ bhh,
    float* __restrict__ hsbuf, unsigned long long* __restrict__ hxt) {
  __shared__ float gh_lds[6 * 256];
  __shared__ unsigned afl[16 * 64 * 4];  // 16KB: [s][lane][4] pk words
  const int tid = threadIdx.x;
  const int w = blockIdx.x;              // 0..15
  const int l = tid & 63, v = tid >> 6;  // wave 0..5
  const int fr = l & 15, fq = l >> 4;
  const int g = v >> 1, half = v & 1;
  const int o = g * 512 + w * 32 + half * 16 + fr;

  // persistent Whh B-fragments (64 VGPR)
  short8 bfrag[16];
#pragma unroll
  for (int s = 0; s < 16; ++s) {
    const float* wp = whh + (size_t)o * 512 + s * 32 + fq * 8;
    float4 w0 = *(const float4*)wp;
    float4 w1 = *(const float4*)(wp + 4);
    short8 bb;
    bb[0] = (short)bf16rn(w0.x); bb[1] = (short)bf16rn(w0.y);
    bb[2] = (short)bf16rn(w0.z); bb[3] = (short)bf16rn(w0.w);
    bb[4] = (short)bf16rn(w1.x); bb[5] = (short)bf16rn(w1.y);
    bb[6] = (short)bf16rn(w1.z); bb[7] = (short)bf16rn(w1.w);
    bfrag[s] = bb;
  }
  const float bo = bhh[o];

  // gate-thread persistent state (threads 0..255): pair (jl, jl+1)
  const int b = tid >> 4, jp = tid & 15, jl = jp * 2;
  const bool gthr = (tid < 256);
  const int lane0 = jp * 4;              // cooperative-load slice
  float hA = 0.f, hB = 0.f;
  float giC0 = 0.f, giC1 = 0.f, giC2 = 0.f, giC3 = 0.f, giC4 = 0.f, giC5 = 0.f;
  float giN0 = 0.f, giN1 = 0.f, giN2 = 0.f, giN3 = 0.f, giN4 = 0.f, giN5 = 0.f;
  if (gthr) {
    float2 h2 = *(const float2*)(h0 + (size_t)b * 512 + w * 32 + jl);
    hA = h2.x; hB = h2.y;
    const float* gb = gi + (size_t)b * 1536 + w * 32 + jl;  // t = 0
    float2 r0 = *(const float2*)(gb);
    float2 r1 = *(const float2*)(gb + 512);
    float2 r2 = *(const float2*)(gb + 1024);
    giC0 = r0.x; giC3 = r0.y; giC1 = r1.x; giC4 = r1.y; giC2 = r2.x; giC5 = r2.y;
  }

  for (int t = 0; t < T_; ++t) {
    // ---- consumer phase (threads 0..255): tagged batch-load h_{t-1} ----
    if (gthr) {
      const unsigned long long* src =
          hxt + (((size_t)(t & 1) * 16 + b) * 64 + lane0) * 4;
      uint4v r[8];
      for (;;) {
#pragma unroll
        for (int q = 0; q < 8; ++q)
          asm volatile("global_load_dwordx4 %0, %1, off sc0 sc1"
                       : "=v"(r[q]) : "v"(src + q * 2));
        asm volatile("s_waitcnt vmcnt(0)" ::: "memory");
        __builtin_amdgcn_sched_barrier(0);
        bool ok = true;
#pragma unroll
        for (int q = 0; q < 8; ++q)
          ok = ok & (r[q].y == (unsigned)t) & (r[q].w == (unsigned)t);
        if (ok) break;
      }
#pragma unroll
      for (int q = 0; q < 8; ++q) {
        uint2 d2 = make_uint2(r[q].x, r[q].z);
        *(uint2*)&afl[(b * 64 + lane0 + (q >> 1)) * 4 + (q & 1) * 2] = d2;
      }
      // off-critical-path work: previous h to hsbuf, gi prefetch for t+1
      if (t > 0)
        *(float2*)(hsbuf + ((size_t)(t - 1) * 16 + b) * 512 + w * 32 + jl) =
            make_float2(hA, hB);
      if (t + 1 < T_) {
        const float* gb = gi + ((size_t)(t + 1) * 16 + b) * 1536 + w * 32 + jl;
        float2 r0 = *(const float2*)(gb);
        float2 r1 = *(const float2*)(gb + 512);
        float2 r2 = *(const float2*)(gb + 1024);
        giN0 = r0.x; giN3 = r0.y; giN1 = r1.x; giN4 = r1.y; giN2 = r2.x; giN5 = r2.y;
      }
    }
    __syncthreads();
    // ---- MFMA phase (all 6 waves): gh = h @ Whh_slice^T ----
    f32x4 a0 = (f32x4)0.f, a1 = (f32x4)0.f, a2 = (f32x4)0.f, a3 = (f32x4)0.f;
#pragma unroll
    for (int s = 0; s < 4; ++s) {
      union { uint4v u; short8 s8; } c0, c1, c2, c3;
      c0.u = *(const uint4v*)&afl[((4 * s + 0) * 64 + l) * 4];
      c1.u = *(const uint4v*)&afl[((4 * s + 1) * 64 + l) * 4];
      c2.u = *(const uint4v*)&afl[((4 * s + 2) * 64 + l) * 4];
      c3.u = *(const uint4v*)&afl[((4 * s + 3) * 64 + l) * 4];
      a0 = __builtin_amdgcn_mfma_f32_16x16x32_bf16(c0.s8, bfrag[4 * s + 0], a0, 0, 0, 0);
      a1 = __builtin_amdgcn_mfma_f32_16x16x32_bf16(c1.s8, bfrag[4 * s + 1], a1, 0, 0, 0);
      a2 = __builtin_amdgcn_mfma_f32_16x16x32_bf16(c2.s8, bfrag[4 * s + 2], a2, 0, 0, 0);
      a3 = __builtin_amdgcn_mfma_f32_16x16x32_bf16(c3.s8, bfrag[4 * s + 3], a3, 0, 0, 0);
    }
#pragma unroll
    for (int j = 0; j < 4; ++j)
      gh_lds[v * 256 + (fq * 4 + j) * 16 + fr] = a0[j] + a1[j] + a2[j] + a3[j] + bo;
    __syncthreads();
    // ---- gate phase (threads 0..255) ----
    if (gthr) {
      const int hh = jl >> 4, c = jl & 15;
      float2 rr = *(const float2*)&gh_lds[(0 + hh) * 256 + b * 16 + c];
      float2 zz = *(const float2*)&gh_lds[(2 + hh) * 256 + b * 16 + c];
      float2 nn = *(const float2*)&gh_lds[(4 + hh) * 256 + b * 16 + c];
      float rgA = __builtin_amdgcn_rcpf(1.f + __expf(-(giC0 + rr.x)));
      float rgB = __builtin_amdgcn_rcpf(1.f + __expf(-(giC3 + rr.y)));
      float zgA = __builtin_amdgcn_rcpf(1.f + __expf(-(giC1 + zz.x)));
      float zgB = __builtin_amdgcn_rcpf(1.f + __expf(-(giC4 + zz.y)));
      float eA = __expf(2.f * (giC2 + rgA * nn.x));
      float eB = __expf(2.f * (giC5 + rgB * nn.y));
      float ngA = 1.f - 2.f * __builtin_amdgcn_rcpf(eA + 1.f);
      float ngB = 1.f - 2.f * __builtin_amdgcn_rcpf(eB + 1.f);
      hA = (1.f - zgA) * ngA + zgA * hA;
      hB = (1.f - zgB) * ngB + zgB * hB;
      // single tagged 8B store = data + release flag in one transaction
      unsigned pk = (unsigned)bf16rn(hA) | ((unsigned)bf16rn(hB) << 16);
      unsigned long long payload =
          (unsigned long long)pk | ((unsigned long long)(unsigned)(t + 1) << 32);
      unsigned long long* dst =
          hxt + (((size_t)((t + 1) & 1) * 16 + w) * 64 + (b | ((jp >> 2) << 4))) * 4 +
          (jp & 3);
      __hip_atomic_store(dst, payload, __ATOMIC_RELAXED, __HIP_MEMORY_SCOPE_AGENT);
      giC0 = giN0; giC1 = giN1; giC2 = giN2;
      giC3 = giN3; giC4 = giN4; giC5 = giN5;
    }
  }
  if (gthr)
    *(float2*)(hsbuf + ((size_t)(T_ - 1) * 16 + b) * 512 + w * 32 + jl) =
        make_float2(hA, hB);
}

// ---------------- fc3 ----------------
__global__ __launch_bounds__(256) void fc3_kernel(
    const float* __restrict__ hs, const float* __restrict__ w3,
    const float* __restrict__ b3, float* __restrict__ out) {
  __shared__ float w[512];
  const int tid = threadIdx.x;
  w[tid] = w3[tid];
  w[tid + 256] = w3[tid + 256];
  __syncthreads();
  const int gidx = blockIdx.x * 256 + tid;  // b*512 + t
  const int b = gidx >> 9, t = gidx & 511;
  const float4* hr = (const float4*)(hs + ((size_t)t * 16 + b) * 512);
  const float4* wr = (const float4*)w;
  float acc = 0.f;
#pragma unroll 8
  for (int kc = 0; kc < 128; ++kc) {
    float4 h = hr[kc], ww = wr[kc];
    acc += h.x * ww.x + h.y * ww.y + h.z * ww.z + h.w * ww.w;
  }
  out[gidx] = acc + b3[0];
}

// ---------------------------------------------------------------------------
extern "C" void kernel_launch(void* const* d_in, const int* in_sizes, int n_in,
                              void* d_out, int out_size, void* d_ws,
                              size_t ws_size, hipStream_t stream) {
  const float* phone = (const float*)d_in[0];
  const float* h0    = (const float*)d_in[1];
  const float* w1    = (const float*)d_in[2];
  const float* b1    = (const float*)d_in[3];
  const float* w2    = (const float*)d_in[4];
  const float* b2    = (const float*)d_in[5];
  const float* fc1w  = (const float*)d_in[6];
  const float* fc1b  = (const float*)d_in[7];
  const float* fc2w  = (const float*)d_in[8];
  const float* fc2b  = (const float*)d_in[9];
  const float* wih   = (const float*)d_in[10];
  const float* whh   = (const float*)d_in[11];
  const float* bih   = (const float*)d_in[12];
  const float* bhh   = (const float*)d_in[13];
  const float* w3    = (const float*)d_in[14];
  const float* b3    = (const float*)d_in[15];
  float* out = (float*)d_out;

  char* ws = (char*)d_ws;
  ushort* out1b = (ushort*)(ws + 0);            // 41,943,040
  ushort* feat2 = (ushort*)(ws + 41943040);     // 25,165,824
  ushort* feat3 = (ushort*)(ws + 67108864);     // 16,777,216 (dead after fc2)
  ushort* feat4 = (ushort*)(ws + 83886080);     //  8,388,608
  float*  gibuf = (float*) (ws + 92274688);     // 50,331,648  [t][b][1536]
  float*  hsbuf = (float*) (ws + 142606336);    // 16,777,216  [t][b][512]
  ushort* w2b   = (ushort*)(ws + 159383552);    //    589,824
  ushort* fc1wb = (ushort*)(ws + 159973376);    //  3,145,728
  ushort* fc2wb = (ushort*)(ws + 163119104);    //  1,048,576
  ushort* wihb  = (ushort*)(ws + 164167680);    //  1,572,864
  // tagged h-exchange buffer overlaps the dead feat3 region
  unsigned long long* hxt = (unsigned long long*)(ws + 67108864);  // 32,768

  f32_to_bf16<<<288, 256, 0, stream>>>(w2, w2b, 73728);
  f32_to_bf16<<<1536, 256, 0, stream>>>(fc1w, fc1wb, 393216);
  f32_to_bf16<<<512, 256, 0, stream>>>(fc2w, fc2wb, 131072);
  f32_to_bf16<<<768, 256, 0, stream>>>(wih, wihb, 196608);

  conv1_kernel<<<1024, 256, 0, stream>>>(phone, w1, b1, out1b);
  gemm_bf16<1, 1><<<dim3(768, 2), 256, 0, stream>>>(out1b, w2b, b2, feat2, 1152, 0, 0);
  gemm_bf16<0, 0><<<dim3(64, 8), 256, 0, stream>>>(feat2, fc1wb, fc1b, feat3, 1536, 1536, 1024);
  gemm_bf16<0, 0><<<dim3(64, 4), 256, 0, stream>>>(feat3, fc2wb, fc2b, feat4, 1024, 1024, 512);
  gemm_bf16<0, 2><<<dim3(64, 12), 256, 0, stream>>>(feat4, wihb, bih, gibuf, 512, 512, 1536);

  // clear tags (replay-safe), stage h0, run recurrence
  hipMemsetAsync(hxt, 0, 32768, stream);
  stage_h0<<<1, 256, 0, stream>>>(h0, hxt);
  gru_persistent<<<16, 384, 0, stream>>>(h0, gibuf, whh, bhh, hsbuf, hxt);

  fc3_kernel<<<32, 256, 0, stream>>>(hsbuf, w3, b3, out);
}

// Round 8
// 1598.678 us; speedup vs baseline: 3.9616x; 1.1499x over previous
//
#include <hip/hip_runtime.h>
#include <hip/hip_bf16.h>
#include <math.h>
#include <stdint.h>

typedef __attribute__((ext_vector_type(8))) short short8;
typedef __attribute__((ext_vector_type(4))) float f32x4;
typedef __attribute__((ext_vector_type(4))) unsigned int uint4v;

#define T_ 512

__device__ __forceinline__ unsigned short bf16rn(float f) {
  union { float f; unsigned u; } x; x.f = f;
  unsigned r = x.u + 0x7FFF + ((x.u >> 16) & 1);
  return (unsigned short)(r >> 16);
}

__device__ __forceinline__ void gload16(const void* gsrc, void* ldst) {
  __builtin_amdgcn_global_load_lds(
      (const __attribute__((address_space(1))) unsigned int*)gsrc,
      (__attribute__((address_space(3))) unsigned int*)ldst, 16, 0, 0);
}

// ---------------- conv1 + pool (fp32 math, bf16 out), 8 frames/block ----------------
__global__ __launch_bounds__(256) void conv1_kernel(
    const float* __restrict__ phone, const float* __restrict__ w1,
    const float* __restrict__ b1, ushort* __restrict__ out1b) {
  __shared__ float ws[128 * 77];
  __shared__ float bs[128];
  __shared__ float xs[8][7][52];
  const int tid = threadIdx.x;
  const int n0 = blockIdx.x * 8;
  for (int idx = tid; idx < 9856; idx += 256) ws[idx] = w1[idx];
  if (tid < 128) bs[tid] = b1[tid];
  for (int idx = tid; idx < 2800; idx += 256) {
    int fi = idx / 350, r = idx - fi * 350;
    int ll = r / 7, c = r - ll * 7;
    xs[fi][c][ll] = phone[(size_t)(n0 + fi) * 350 + r];
  }
  __syncthreads();

  const int o = tid >> 1, ph = tid & 1;
  const float* wo = ws + o * 77;
  const float bb = bs[o];
  for (int fi = 0; fi < 8; ++fi) {
    float acc0[10], acc1[10];
#pragma unroll
    for (int q = 0; q < 10; ++q) { acc0[q] = 0.f; acc1[q] = 0.f; }
    for (int i = 0; i < 7; ++i) {
      float wr[11];
#pragma unroll
      for (int k = 0; k < 11; ++k) wr[k] = wo[i * 11 + k];
#pragma unroll
      for (int q = 0; q < 10; ++q) {
        int p = ph * 10 + q;
        int base = 2 * p;
        float xv[12];
#pragma unroll
        for (int j = 0; j < 12; ++j) xv[j] = xs[fi][i][base + j];
        float s0 = 0.f, s1 = 0.f;
#pragma unroll
        for (int k = 0; k < 11; ++k) {
          s0 += xv[k] * wr[k];
          s1 += xv[k + 1] * wr[k];
        }
        acc0[q] += s0;
        acc1[q] += s1;
      }
    }
#pragma unroll
    for (int q = 0; q < 10; ++q) {
      int p = ph * 10 + q;
      out1b[((size_t)(n0 + fi) * 128 + o) * 20 + p] =
          bf16rn(fmaxf(acc0[q], acc1[q]) + bb);
    }
  }
}

// ---------------- fp32 -> bf16 convert ----------------
__global__ __launch_bounds__(256) void f32_to_bf16(
    const float* __restrict__ src, ushort* __restrict__ dst, int n4) {
  int i = blockIdx.x * 256 + threadIdx.x;
  if (i < n4) {
    float4 v = ((const float4*)src)[i];
    ushort4 o;
    o.x = bf16rn(v.x); o.y = bf16rn(v.y); o.z = bf16rn(v.z); o.w = bf16rn(v.w);
    ((ushort4*)dst)[i] = o;
  }
}

// ---------------- stage h0 -> tagged bf16 fragments (parity-0 buffer, tag 0) ----------------
__global__ __launch_bounds__(256) void stage_h0(
    const float* __restrict__ h0, unsigned long long* __restrict__ hxt) {
  const int tid = threadIdx.x;
  const int b = tid >> 4, x = tid & 15;
#pragma unroll
  for (int q = 0; q < 16; ++q) {
    int d = (x + q * 16) * 2;
    int s = d >> 5, fqq = (d >> 3) & 3, k = (d & 7) >> 1;
    int lane = b | (fqq << 4);
    float2 h2 = *(const float2*)(h0 + (size_t)b * 512 + d);
    unsigned pk = (unsigned)bf16rn(h2.x) | ((unsigned)bf16rn(h2.y) << 16);
    hxt[((size_t)s * 64 + lane) * 4 + k] = (unsigned long long)pk;  // tag = 0
  }
}

// ---------------- bf16 MFMA GEMM: C = A @ W^T + bias ----------------
template <int AM, int EM>
__global__ __launch_bounds__(256) void gemm_bf16(
    const ushort* __restrict__ A, const ushort* __restrict__ W,
    const float* __restrict__ bias, void* __restrict__ Cout,
    int K, int lda, int ldc) {
  __shared__ ushort As[128 * 64];
  __shared__ ushort Bs[128 * 64];
  __shared__ ushort tbl[1152];
  const int tid = threadIdx.x;
  const int l = tid & 63, wv = tid >> 6;
  const int wr = wv >> 1, wc = wv & 1;
  const int fr = l & 15, fq = l >> 4;
  const int bm0 = blockIdx.x * 128, bn0 = blockIdx.y * 128;

  if (AM == 1) {
    for (int idx = tid; idx < 1152; idx += 256) {
      int i2 = idx / 9, kp = idx - i2 * 9;
      tbl[idx] = (ushort)(i2 * 20 + kp);
    }
    __syncthreads();
  }

  f32x4 acc[4][4];
#pragma unroll
  for (int mi = 0; mi < 4; ++mi)
#pragma unroll
    for (int ni = 0; ni < 4; ++ni) acc[mi][ni] = (f32x4)0.f;

  const int pr8 = l >> 3;
  const int pc = l & 7;
  const int nkt = K >> 6;
  for (int kt = 0; kt < nkt; ++kt) {
    const int k0 = kt << 6;
#pragma unroll
    for (int i = 0; i < 4; ++i) {
      int q = wv * 4 + i;
      int prow = q * 8 + pr8;
      int lc = pc ^ (prow & 7);
      gload16(W + (size_t)(bn0 + prow) * K + k0 + lc * 8, &Bs[q * 512]);
    }
    if (AM == 0) {
#pragma unroll
      for (int i = 0; i < 4; ++i) {
        int q = wv * 4 + i;
        int prow = q * 8 + pr8;
        int lc = pc ^ (prow & 7);
        gload16(A + (size_t)(bm0 + prow) * lda + k0 + lc * 8, &As[q * 512]);
      }
    } else {
      // im2col gather via LDS index table
#pragma unroll
      for (int q = 0; q < 16; ++q) {
        int idx = tid + q * 256;        // 4096 pair items
        int row = idx >> 5, c0 = (idx & 31) * 2;
        int m = bm0 + row;
        int n = m / 12, pos = m - n * 12;
        int kk = k0 + c0;
        const ushort* an = A + (size_t)n * 2560 + pos;
        uint e0 = an[tbl[kk]];
        uint e1 = an[tbl[kk + 1]];
        *(uint*)&As[row * 64 + (((c0 >> 3) ^ (row & 7)) << 3) + (c0 & 7)] =
            e0 | (e1 << 16);
      }
    }
    __syncthreads();
#pragma unroll
    for (int ks = 0; ks < 2; ++ks) {
      short8 af[4], bfr[4];
#pragma unroll
      for (int mi = 0; mi < 4; ++mi) {
        int row = wr * 64 + mi * 16 + fr;
        af[mi] = *(const short8*)&As[row * 64 + (((ks * 4 + fq) ^ (row & 7)) << 3)];
      }
#pragma unroll
      for (int ni = 0; ni < 4; ++ni) {
        int row = wc * 64 + ni * 16 + fr;
        bfr[ni] = *(const short8*)&Bs[row * 64 + (((ks * 4 + fq) ^ (row & 7)) << 3)];
      }
#pragma unroll
      for (int mi = 0; mi < 4; ++mi)
#pragma unroll
        for (int ni = 0; ni < 4; ++ni)
          acc[mi][ni] = __builtin_amdgcn_mfma_f32_16x16x32_bf16(
              af[mi], bfr[ni], acc[mi][ni], 0, 0, 0);
    }
    __syncthreads();
  }

#pragma unroll
  for (int ni = 0; ni < 4; ++ni) {
    int col = bn0 + wc * 64 + ni * 16 + fr;
    float bv = bias[col];
#pragma unroll
    for (int mi = 0; mi < 4; ++mi) {
      int mbase = bm0 + wr * 64 + mi * 16 + fq * 4;
      if (EM == 0) {
        ushort* C = (ushort*)Cout;
#pragma unroll
        for (int j = 0; j < 4; ++j)
          C[(size_t)(mbase + j) * ldc + col] = bf16rn(acc[mi][ni][j] + bv);
      } else if (EM == 1) {
        ushort* C = (ushort*)Cout;
#pragma unroll
        for (int j = 0; j < 4; j += 2) {
          int m = mbase + j;
          int n = m / 12, pos = m - n * 12;
          float v = fmaxf(acc[mi][ni][j], acc[mi][ni][j + 1]) + bv;
          C[(size_t)n * 1536 + col * 6 + (pos >> 1)] = bf16rn(v);
        }
      } else {
        float* C = (float*)Cout;
#pragma unroll
        for (int j = 0; j < 4; ++j) {
          int m = mbase + j;
          int b = m >> 9, tt = m & 511;
          C[((size_t)tt * 16 + b) * 1536 + col] = acc[mi][ni][j] + bv;
        }
      }
    }
  }
}

// ---------------- persistent GRU: tagged exchange + dedicated poller waves ----------------
// 16 WGs x 384 thr.  Waves 0-3 = gate/producer threads (also MFMA); waves 4-5 =
// dedicated pollers (also MFMA).  Per step: phase1 = all-wave MFMA; phase2 =
// {gates compute + tagged agent store for t+1} CONCURRENT WITH {pollers spin on
// parity(t+1) tags via sc0 sc1 LLC-coherent loads and deposit into LDS}.
// sc1 on polls is REQUIRED: sc0-only reads the local XCD L2, which caches a
// stale clean line and never sees remote producers (rounds 6/7 hang).
__global__ __launch_bounds__(384) void gru_persistent(
    const float* __restrict__ h0, const float* __restrict__ gi,
    const float* __restrict__ whh, const float* __restrict__ bhh,
    float* __restrict__ hsbuf, unsigned long long* __restrict__ hxt) {
  __shared__ float gh_lds[6 * 256];
  __shared__ unsigned afl[16 * 64 * 4];  // 16KB: [s][lane][4] pk words
  const int tid = threadIdx.x;
  const int w = blockIdx.x;              // 0..15
  const int l = tid & 63, v = tid >> 6;  // wave 0..5
  const int fr = l & 15, fq = l >> 4;
  const int g = v >> 1, half = v & 1;
  const int o = g * 512 + w * 32 + half * 16 + fr;

  // persistent Whh B-fragments (64 VGPR, all waves)
  short8 bfrag[16];
#pragma unroll
  for (int s = 0; s < 16; ++s) {
    const float* wp = whh + (size_t)o * 512 + s * 32 + fq * 8;
    float4 w0 = *(const float4*)wp;
    float4 w1 = *(const float4*)(wp + 4);
    short8 bb;
    bb[0] = (short)bf16rn(w0.x); bb[1] = (short)bf16rn(w0.y);
    bb[2] = (short)bf16rn(w0.z); bb[3] = (short)bf16rn(w0.w);
    bb[4] = (short)bf16rn(w1.x); bb[5] = (short)bf16rn(w1.y);
    bb[6] = (short)bf16rn(w1.z); bb[7] = (short)bf16rn(w1.w);
    bfrag[s] = bb;
  }
  const float bo = bhh[o];

  // gate-thread persistent state (threads 0..255): pair (jl, jl+1)
  const int b = tid >> 4, jp = tid & 15, jl = jp * 2;
  const bool gthr = (tid < 256);
  const int pt = tid - 256;              // poller index 0..127 (waves 4,5)
  float hA = 0.f, hB = 0.f;
  float giC0 = 0.f, giC1 = 0.f, giC2 = 0.f, giC3 = 0.f, giC4 = 0.f, giC5 = 0.f;
  float giN0 = 0.f, giN1 = 0.f, giN2 = 0.f, giN3 = 0.f, giN4 = 0.f, giN5 = 0.f;
  if (gthr) {
    float2 h2 = *(const float2*)(h0 + (size_t)b * 512 + w * 32 + jl);
    hA = h2.x; hB = h2.y;
    const float* g0 = gi + (size_t)b * 1536 + w * 32 + jl;           // gi[0]
    float2 r0 = *(const float2*)(g0);
    float2 r1 = *(const float2*)(g0 + 512);
    float2 r2 = *(const float2*)(g0 + 1024);
    giC0 = r0.x; giC3 = r0.y; giC1 = r1.x; giC4 = r1.y; giC2 = r2.x; giC5 = r2.y;
    const float* g1 = gi + (size_t)(16 + b) * 1536 + w * 32 + jl;    // gi[1]
    float2 s0 = *(const float2*)(g1);
    float2 s1 = *(const float2*)(g1 + 512);
    float2 s2 = *(const float2*)(g1 + 1024);
    giN0 = s0.x; giN3 = s0.y; giN1 = s1.x; giN4 = s1.y; giN2 = s2.x; giN5 = s2.y;
  }

  // ---- prologue: pollers fetch h_0 (parity 0, tag 0) ----
  if (!gthr) {
    const unsigned long long* base = hxt + pt * 2;
    uint4v r[16];
    for (;;) {
#pragma unroll
      for (int m = 0; m < 16; ++m)
        asm volatile("global_load_dwordx4 %0, %1, off sc0 sc1"
                     : "=v"(r[m]) : "v"(base + m * 256));
      asm volatile("s_waitcnt vmcnt(0)" ::: "memory");
      __builtin_amdgcn_sched_barrier(0);
      bool ok = true;
#pragma unroll
      for (int m = 0; m < 16; ++m)
        ok = ok & (r[m].y == 0u) & (r[m].w == 0u);
      if (ok) break;
    }
#pragma unroll
    for (int m = 0; m < 16; ++m)
      *(uint2*)&afl[pt * 2 + m * 256] = make_uint2(r[m].x, r[m].z);
  }
  __syncthreads();

  for (int t = 0; t < T_; ++t) {
    // ---- phase 1: all 6 waves MFMA gh = h_t @ Whh_slice^T ----
    f32x4 a0 = (f32x4)0.f, a1 = (f32x4)0.f, a2 = (f32x4)0.f, a3 = (f32x4)0.f;
#pragma unroll
    for (int s = 0; s < 4; ++s) {
      union { uint4v u; short8 s8; } c0, c1, c2, c3;
      c0.u = *(const uint4v*)&afl[((4 * s + 0) * 64 + l) * 4];
      c1.u = *(const uint4v*)&afl[((4 * s + 1) * 64 + l) * 4];
      c2.u = *(const uint4v*)&afl[((4 * s + 2) * 64 + l) * 4];
      c3.u = *(const uint4v*)&afl[((4 * s + 3) * 64 + l) * 4];
      a0 = __builtin_amdgcn_mfma_f32_16x16x32_bf16(c0.s8, bfrag[4 * s + 0], a0, 0, 0, 0);
      a1 = __builtin_amdgcn_mfma_f32_16x16x32_bf16(c1.s8, bfrag[4 * s + 1], a1, 0, 0, 0);
      a2 = __builtin_amdgcn_mfma_f32_16x16x32_bf16(c2.s8, bfrag[4 * s + 2], a2, 0, 0, 0);
      a3 = __builtin_amdgcn_mfma_f32_16x16x32_bf16(c3.s8, bfrag[4 * s + 3], a3, 0, 0, 0);
    }
#pragma unroll
    for (int j = 0; j < 4; ++j)
      gh_lds[v * 256 + (fq * 4 + j) * 16 + fr] = a0[j] + a1[j] + a2[j] + a3[j] + bo;
    __syncthreads();

    // ---- phase 2: gates+store (waves 0-3) || poll t+1 (waves 4-5) ----
    if (gthr) {
      const int hh = jl >> 4, c = jl & 15;
      float2 rr = *(const float2*)&gh_lds[(0 + hh) * 256 + b * 16 + c];
      float2 zz = *(const float2*)&gh_lds[(2 + hh) * 256 + b * 16 + c];
      float2 nn = *(const float2*)&gh_lds[(4 + hh) * 256 + b * 16 + c];
      float rgA = __builtin_amdgcn_rcpf(1.f + __expf(-(giC0 + rr.x)));
      float rgB = __builtin_amdgcn_rcpf(1.f + __expf(-(giC3 + rr.y)));
      float zgA = __builtin_amdgcn_rcpf(1.f + __expf(-(giC1 + zz.x)));
      float zgB = __builtin_amdgcn_rcpf(1.f + __expf(-(giC4 + zz.y)));
      float eA = __expf(2.f * (giC2 + rgA * nn.x));
      float eB = __expf(2.f * (giC5 + rgB * nn.y));
      float ngA = 1.f - 2.f * __builtin_amdgcn_rcpf(eA + 1.f);
      float ngB = 1.f - 2.f * __builtin_amdgcn_rcpf(eB + 1.f);
      hA = (1.f - zgA) * ngA + zgA * hA;
      hB = (1.f - zgB) * ngB + zgB * hB;
      // tagged 8B agent store = data + release flag in one transaction
      if (t + 1 < T_) {
        unsigned pk = (unsigned)bf16rn(hA) | ((unsigned)bf16rn(hB) << 16);
        unsigned long long payload =
            (unsigned long long)pk | ((unsigned long long)(unsigned)(t + 1) << 32);
        unsigned long long* dst =
            hxt + (((size_t)((t + 1) & 1) * 16 + w) * 64 + (b | ((jp >> 2) << 4))) * 4 +
            (jp & 3);
        __hip_atomic_store(dst, payload, __ATOMIC_RELAXED, __HIP_MEMORY_SCOPE_AGENT);
      }
      // off-critical-path: fp32 h for fc3; shift gi pipeline; prefetch gi[t+2]
      *(float2*)(hsbuf + ((size_t)t * 16 + b) * 512 + w * 32 + jl) =
          make_float2(hA, hB);
      giC0 = giN0; giC1 = giN1; giC2 = giN2;
      giC3 = giN3; giC4 = giN4; giC5 = giN5;
      if (t + 2 < T_) {
        const float* gb = gi + ((size_t)(t + 2) * 16 + b) * 1536 + w * 32 + jl;
        float2 r0 = *(const float2*)(gb);
        float2 r1 = *(const float2*)(gb + 512);
        float2 r2 = *(const float2*)(gb + 1024);
        giN0 = r0.x; giN3 = r0.y; giN1 = r1.x; giN4 = r1.y; giN2 = r2.x; giN5 = r2.y;
      }
    } else if (t + 1 < T_) {
      const unsigned long long* base =
          hxt + (size_t)((t + 1) & 1) * 4096 + pt * 2;
      const unsigned tag = (unsigned)(t + 1);
      uint4v r[16];
      for (;;) {
#pragma unroll
        for (int m = 0; m < 16; ++m)
          asm volatile("global_load_dwordx4 %0, %1, off sc0 sc1"
                       : "=v"(r[m]) : "v"(base + m * 256));
        asm volatile("s_waitcnt vmcnt(0)" ::: "memory");
        __builtin_amdgcn_sched_barrier(0);
        bool ok = true;
#pragma unroll
        for (int m = 0; m < 16; ++m)
          ok = ok & (r[m].y == tag) & (r[m].w == tag);
        if (ok) break;
      }
#pragma unroll
      for (int m = 0; m < 16; ++m)
        *(uint2*)&afl[pt * 2 + m * 256] = make_uint2(r[m].x, r[m].z);
    }
    __syncthreads();
  }
}

// ---------------- fc3 ----------------
__global__ __launch_bounds__(256) void fc3_kernel(
    const float* __restrict__ hs, const float* __restrict__ w3,
    const float* __restrict__ b3, float* __restrict__ out) {
  __shared__ float w[512];
  const int tid = threadIdx.x;
  w[tid] = w3[tid];
  w[tid + 256] = w3[tid + 256];
  __syncthreads();
  const int gidx = blockIdx.x * 256 + tid;  // b*512 + t
  const int b = gidx >> 9, t = gidx & 511;
  const float4* hr = (const float4*)(hs + ((size_t)t * 16 + b) * 512);
  const float4* wr = (const float4*)w;
  float acc = 0.f;
#pragma unroll 8
  for (int kc = 0; kc < 128; ++kc) {
    float4 h = hr[kc], ww = wr[kc];
    acc += h.x * ww.x + h.y * ww.y + h.z * ww.z + h.w * ww.w;
  }
  out[gidx] = acc + b3[0];
}

// ---------------------------------------------------------------------------
extern "C" void kernel_launch(void* const* d_in, const int* in_sizes, int n_in,
                              void* d_out, int out_size, void* d_ws,
                              size_t ws_size, hipStream_t stream) {
  const float* phone = (const float*)d_in[0];
  const float* h0    = (const float*)d_in[1];
  const float* w1    = (const float*)d_in[2];
  const float* b1    = (const float*)d_in[3];
  const float* w2    = (const float*)d_in[4];
  const float* b2    = (const float*)d_in[5];
  const float* fc1w  = (const float*)d_in[6];
  const float* fc1b  = (const float*)d_in[7];
  const float* fc2w  = (const float*)d_in[8];
  const float* fc2b  = (const float*)d_in[9];
  const float* wih   = (const float*)d_in[10];
  const float* whh   = (const float*)d_in[11];
  const float* bih   = (const float*)d_in[12];
  const float* bhh   = (const float*)d_in[13];
  const float* w3    = (const float*)d_in[14];
  const float* b3    = (const float*)d_in[15];
  float* out = (float*)d_out;

  char* ws = (char*)d_ws;
  ushort* out1b = (ushort*)(ws + 0);            // 41,943,040
  ushort* feat2 = (ushort*)(ws + 41943040);     // 25,165,824
  ushort* feat3 = (ushort*)(ws + 67108864);     // 16,777,216 (dead after fc2)
  ushort* feat4 = (ushort*)(ws + 83886080);     //  8,388,608
  float*  gibuf = (float*) (ws + 92274688);     // 50,331,648  [t][b][1536]
  float*  hsbuf = (float*) (ws + 142606336);    // 16,777,216  [t][b][512]
  ushort* w2b   = (ushort*)(ws + 159383552);    //    589,824
  ushort* fc1wb = (ushort*)(ws + 159973376);    //  3,145,728
  ushort* fc2wb = (ushort*)(ws + 163119104);    //  1,048,576
  ushort* wihb  = (ushort*)(ws + 164167680);    //  1,572,864
  // tagged h-exchange buffer (2 x 32KB parity) overlaps the dead feat3 region
  unsigned long long* hxt = (unsigned long long*)(ws + 67108864);

  f32_to_bf16<<<288, 256, 0, stream>>>(w2, w2b, 73728);
  f32_to_bf16<<<1536, 256, 0, stream>>>(fc1w, fc1wb, 393216);
  f32_to_bf16<<<512, 256, 0, stream>>>(fc2w, fc2wb, 131072);
  f32_to_bf16<<<768, 256, 0, stream>>>(wih, wihb, 196608);

  conv1_kernel<<<1024, 256, 0, stream>>>(phone, w1, b1, out1b);
  gemm_bf16<1, 1><<<dim3(768, 2), 256, 0, stream>>>(out1b, w2b, b2, feat2, 1152, 0, 0);
  gemm_bf16<0, 0><<<dim3(64, 8), 256, 0, stream>>>(feat2, fc1wb, fc1b, feat3, 1536, 1536, 1024);
  gemm_bf16<0, 0><<<dim3(64, 4), 256, 0, stream>>>(feat3, fc2wb, fc2b, feat4, 1024, 1024, 512);
  gemm_bf16<0, 2><<<dim3(64, 12), 256, 0, stream>>>(feat4, wihb, bih, gibuf, 512, 512, 1536);

  // clear BOTH parity tag buffers (replay-safe), stage h0, run recurrence
  hipMemsetAsync(hxt, 0, 65536, stream);
  stage_h0<<<1, 256, 0, stream>>>(h0, hxt);
  gru_persistent<<<16, 384, 0, stream>>>(h0, gibuf, whh, bhh, hsbuf, hxt);

  fc3_kernel<<<32, 256, 0, stream>>>(hsbuf, w3, b3, out);
}